// Round 1
// baseline (382.629 us; speedup 1.0000x reference)
//
#include <hip/hip_runtime.h>
#include <stdint.h>

// Problem constants
#define BB 4
#define LL 2048
#define DD 1024

typedef __attribute__((ext_vector_type(4))) float f32x4;
typedef __attribute__((ext_vector_type(8))) __bf16 bf16x8;
typedef __attribute__((ext_vector_type(4))) unsigned short u16x4;
typedef unsigned short u16;

// ---------- bf16 helpers (manual RNE, no header-type dependence) ----------
__device__ __forceinline__ u16 f2bf(float x){
  unsigned u = __float_as_uint(x);
  u += 0x7FFFu + ((u >> 16) & 1u);
  return (u16)(u >> 16);
}
__device__ __forceinline__ float bf2f(u16 h){
  return __uint_as_float(((unsigned)h) << 16);
}

// ---------- async global->LDS staging (16B/lane) ----------
__device__ __forceinline__ void gload16(const u16* g, u16* l){
  __builtin_amdgcn_global_load_lds((const __attribute__((address_space(1))) unsigned*)g,
                                   (__attribute__((address_space(3))) unsigned*)l,
                                   16, 0, 0);
}

// stage a [128][64] bf16 tile from row-major src (ld elems) into linear LDS [128][64]
__device__ __forceinline__ void stage_tile(u16* lds, const u16* src, int ld, int wave, int lane){
  const int r0 = lane >> 3;          // 0..7 row within 8-row group
  const int ce = (lane & 7) << 3;    // elem col (8 bf16 = 16B chunks)
  #pragma unroll
  for (int j = 0; j < 4; ++j){
    const int rb = wave*32 + j*8;    // wave-uniform row base
    gload16(src + (size_t)(rb + r0)*ld + ce, lds + rb*64);
  }
}

__device__ __forceinline__ bf16x8 frag_ld(const u16* t, int row, int ko){
  return __builtin_bit_cast(bf16x8, *reinterpret_cast<const f32x4*>(t + row*64 + ko));
}

// ---------- kernel: f32 -> bf16 hi/lo split (lo may be null) ----------
__global__ void split_k(const float* __restrict__ src, u16* __restrict__ hi,
                        u16* __restrict__ lo, int n4){
  const int stride = gridDim.x * blockDim.x;
  for (int i = blockIdx.x*blockDim.x + threadIdx.x; i < n4; i += stride){
    f32x4 v = reinterpret_cast<const f32x4*>(src)[i];
    u16x4 h, l;
    #pragma unroll
    for (int j = 0; j < 4; ++j){
      u16 hb = f2bf(v[j]);
      h[j] = hb;
      l[j] = f2bf(v[j] - bf2f(hb));
    }
    reinterpret_cast<u16x4*>(hi)[i] = h;
    if (lo) reinterpret_cast<u16x4*>(lo)[i] = l;
  }
}

// ---------- kernel: t1 = f1 @ W1^T + b1, split-precision (3-product), reg-staged ----------
// M=8192 (B*L), N=1024, K=1024. Writes t1_hi/t1_lo bf16.
__global__ __launch_bounds__(256,2) void gemm_t1_k(const float* __restrict__ f1,
                                                   const float* __restrict__ W1,
                                                   const float* __restrict__ b1,
                                                   u16* __restrict__ t1h, u16* __restrict__ t1l){
  __shared__ __align__(16) u16 Ah[128*64];
  __shared__ __align__(16) u16 Al[128*64];
  __shared__ __align__(16) u16 Bh[128*64];
  __shared__ __align__(16) u16 Bl[128*64];
  const int bm = blockIdx.x >> 3, bn = blockIdx.x & 7;  // 64 x 8 tiles
  const int tid = threadIdx.x, wave = tid>>6, lane = tid&63;
  const int wr = wave>>1, wc = wave&1;
  f32x4 acc[4][4];
  #pragma unroll
  for (int i=0;i<4;i++)
    #pragma unroll
    for (int j=0;j<4;j++) acc[i][j] = (f32x4){0.f,0.f,0.f,0.f};

  for (int k0 = 0; k0 < DD; k0 += 64){
    __syncthreads();
    // stage + split A (f1 rows)
    #pragma unroll
    for (int t = tid; t < 2048; t += 256){
      const int row = t >> 4, c4 = (t & 15) << 2;
      f32x4 v = *reinterpret_cast<const f32x4*>(f1 + (size_t)(bm*128 + row)*DD + k0 + c4);
      u16x4 h, l;
      #pragma unroll
      for (int j=0;j<4;j++){ u16 hb = f2bf(v[j]); h[j]=hb; l[j]=f2bf(v[j]-bf2f(hb)); }
      *reinterpret_cast<u16x4*>(Ah + row*64 + c4) = h;
      *reinterpret_cast<u16x4*>(Al + row*64 + c4) = l;
    }
    // stage + split B (W1 rows = output cols e)
    #pragma unroll
    for (int t = tid; t < 2048; t += 256){
      const int row = t >> 4, c4 = (t & 15) << 2;
      f32x4 v = *reinterpret_cast<const f32x4*>(W1 + (size_t)(bn*128 + row)*DD + k0 + c4);
      u16x4 h, l;
      #pragma unroll
      for (int j=0;j<4;j++){ u16 hb = f2bf(v[j]); h[j]=hb; l[j]=f2bf(v[j]-bf2f(hb)); }
      *reinterpret_cast<u16x4*>(Bh + row*64 + c4) = h;
      *reinterpret_cast<u16x4*>(Bl + row*64 + c4) = l;
    }
    __syncthreads();
    #pragma unroll
    for (int kk=0;kk<2;kk++){
      const int ko = kk*32 + ((lane>>4)<<3);
      bf16x8 ah[4], al[4], bh[4], bl[4];
      #pragma unroll
      for (int mi=0;mi<4;mi++){
        const int r = wr*64 + mi*16 + (lane&15);
        ah[mi] = frag_ld(Ah, r, ko);
        al[mi] = frag_ld(Al, r, ko);
      }
      #pragma unroll
      for (int ni=0;ni<4;ni++){
        const int r = wc*64 + ni*16 + (lane&15);
        bh[ni] = frag_ld(Bh, r, ko);
        bl[ni] = frag_ld(Bl, r, ko);
      }
      #pragma unroll
      for (int mi=0;mi<4;mi++)
        #pragma unroll
        for (int ni=0;ni<4;ni++){
          acc[mi][ni] = __builtin_amdgcn_mfma_f32_16x16x32_bf16(ah[mi], bh[ni], acc[mi][ni], 0,0,0);
          acc[mi][ni] = __builtin_amdgcn_mfma_f32_16x16x32_bf16(ah[mi], bl[ni], acc[mi][ni], 0,0,0);
          acc[mi][ni] = __builtin_amdgcn_mfma_f32_16x16x32_bf16(al[mi], bh[ni], acc[mi][ni], 0,0,0);
        }
    }
  }
  // epilogue: + b1, split to hi/lo
  #pragma unroll
  for (int mi=0;mi<4;mi++)
    #pragma unroll
    for (int ni=0;ni<4;ni++){
      const int r = bm*128 + wr*64 + mi*16 + ((lane>>4)<<2);
      const int c = bn*128 + wc*64 + ni*16 + (lane&15);
      const float bias = b1[c];
      #pragma unroll
      for (int j=0;j<4;j++){
        const float x = acc[mi][ni][j] + bias;
        const u16 hb = f2bf(x);
        t1h[(size_t)(r+j)*DD + c] = hb;
        t1l[(size_t)(r+j)*DD + c] = f2bf(x - bf2f(hb));
      }
    }
}

// ---------- kernel: sim[b] = t1[b] @ f2[b]^T (split 3-product), f32 out ----------
__global__ __launch_bounds__(256,2) void gemm_sim_k(const u16* __restrict__ t1h, const u16* __restrict__ t1l,
                                                    const u16* __restrict__ f2h, const u16* __restrict__ f2l,
                                                    float* __restrict__ sim){
  __shared__ __align__(16) u16 Ah[128*64];
  __shared__ __align__(16) u16 Al[128*64];
  __shared__ __align__(16) u16 Bh[128*64];
  __shared__ __align__(16) u16 Bl[128*64];
  const int b = blockIdx.y;
  const int bm = blockIdx.x >> 4, bn = blockIdx.x & 15;  // 16 x 16 tiles
  const int tid = threadIdx.x, wave = tid>>6, lane = tid&63;
  const int wr = wave>>1, wc = wave&1;
  const size_t ab = (size_t)b*LL*DD;
  const u16* A_h = t1h + ab + (size_t)(bm*128)*DD;
  const u16* A_l = t1l + ab + (size_t)(bm*128)*DD;
  const u16* B_h = f2h + ab + (size_t)(bn*128)*DD;
  const u16* B_l = f2l + ab + (size_t)(bn*128)*DD;
  f32x4 acc[4][4];
  #pragma unroll
  for (int i=0;i<4;i++)
    #pragma unroll
    for (int j=0;j<4;j++) acc[i][j] = (f32x4){0.f,0.f,0.f,0.f};

  for (int k0 = 0; k0 < DD; k0 += 64){
    __syncthreads();
    stage_tile(Ah, A_h + k0, DD, wave, lane);
    stage_tile(Al, A_l + k0, DD, wave, lane);
    stage_tile(Bh, B_h + k0, DD, wave, lane);
    stage_tile(Bl, B_l + k0, DD, wave, lane);
    __syncthreads();
    #pragma unroll
    for (int kk=0;kk<2;kk++){
      const int ko = kk*32 + ((lane>>4)<<3);
      bf16x8 ah[4], al[4], bh[4], bl[4];
      #pragma unroll
      for (int mi=0;mi<4;mi++){
        const int r = wr*64 + mi*16 + (lane&15);
        ah[mi] = frag_ld(Ah, r, ko);
        al[mi] = frag_ld(Al, r, ko);
      }
      #pragma unroll
      for (int ni=0;ni<4;ni++){
        const int r = wc*64 + ni*16 + (lane&15);
        bh[ni] = frag_ld(Bh, r, ko);
        bl[ni] = frag_ld(Bl, r, ko);
      }
      #pragma unroll
      for (int mi=0;mi<4;mi++)
        #pragma unroll
        for (int ni=0;ni<4;ni++){
          acc[mi][ni] = __builtin_amdgcn_mfma_f32_16x16x32_bf16(ah[mi], bh[ni], acc[mi][ni], 0,0,0);
          acc[mi][ni] = __builtin_amdgcn_mfma_f32_16x16x32_bf16(ah[mi], bl[ni], acc[mi][ni], 0,0,0);
          acc[mi][ni] = __builtin_amdgcn_mfma_f32_16x16x32_bf16(al[mi], bh[ni], acc[mi][ni], 0,0,0);
        }
    }
  }
  float* C = sim + (size_t)b*LL*LL;
  const int m0 = bm*128, n0 = bn*128;
  #pragma unroll
  for (int mi=0;mi<4;mi++)
    #pragma unroll
    for (int ni=0;ni<4;ni++){
      const int r = m0 + wr*64 + mi*16 + ((lane>>4)<<2);
      const int c = n0 + wc*64 + ni*16 + (lane&15);
      #pragma unroll
      for (int j=0;j<4;j++)
        C[(size_t)(r+j)*LL + c] = acc[mi][ni][j];
    }
}

// ---------- kernel: row softmax f32->bf16 in place (attn at row byte offset row*8192) ----------
__global__ __launch_bounds__(256) void softmax_k(float* __restrict__ sim){
  const int row = blockIdx.x;            // b*2048 + l
  float* p = sim + (size_t)row * LL;
  const int tid = threadIdx.x, wave = tid>>6, lane = tid&63;
  f32x4 x0 = reinterpret_cast<const f32x4*>(p)[tid];
  f32x4 x1 = reinterpret_cast<const f32x4*>(p)[tid + 256];
  float mx = fmaxf(fmaxf(fmaxf(x0[0],x0[1]), fmaxf(x0[2],x0[3])),
                   fmaxf(fmaxf(x1[0],x1[1]), fmaxf(x1[2],x1[3])));
  #pragma unroll
  for (int o = 32; o; o >>= 1) mx = fmaxf(mx, __shfl_xor(mx, o, 64));
  __shared__ float red[8];
  if (lane == 0) red[wave] = mx;
  __syncthreads();
  mx = fmaxf(fmaxf(red[0], red[1]), fmaxf(red[2], red[3]));
  float e0[4], e1[4], s = 0.f;
  #pragma unroll
  for (int j=0;j<4;j++){ e0[j] = __expf(x0[j]-mx); s += e0[j]; }
  #pragma unroll
  for (int j=0;j<4;j++){ e1[j] = __expf(x1[j]-mx); s += e1[j]; }
  #pragma unroll
  for (int o = 32; o; o >>= 1) s += __shfl_xor(s, o, 64);
  if (lane == 0) red[4+wave] = s;
  __syncthreads();
  s = (red[4]+red[5]) + (red[6]+red[7]);
  const float inv = 1.0f / s;
  u16* ob = reinterpret_cast<u16*>(p);   // row base byte = row*8192
  u16x4 w0, w1;
  #pragma unroll
  for (int j=0;j<4;j++){ w0[j] = f2bf(e0[j]*inv); w1[j] = f2bf(e1[j]*inv); }
  reinterpret_cast<u16x4*>(ob)[tid]       = w0;
  reinterpret_cast<u16x4*>(ob)[tid + 256] = w1;
}

// ---------- kernel: bf16 transpose per batch [2048][1024] -> [1024][2048] ----------
__global__ void transpose_k(const u16* __restrict__ in, u16* __restrict__ out){
  __shared__ u16 t[32][33];
  const int b = blockIdx.z;
  const int e0 = blockIdx.x*32, m0 = blockIdx.y*32;
  const u16* src = in  + (size_t)b*LL*DD;
  u16* dst       = out + (size_t)b*DD*LL;
  for (int j = threadIdx.y; j < 32; j += 8)
    t[j][threadIdx.x] = src[(size_t)(m0+j)*DD + e0 + threadIdx.x];
  __syncthreads();
  for (int j = threadIdx.y; j < 32; j += 8)
    dst[(size_t)(e0+j)*LL + m0 + threadIdx.x] = t[threadIdx.x][j];
}

// ---------- generic bf16 1-product GEMM (A [.,K] K-contig, B "B^T" [N][K] K-contig) ----------
// EPI=0: C f32 (+optional bias per col). EPI=1: scatter-transposed bf16 ZT[b][d][m].
template<int EPI>
__global__ __launch_bounds__(256,2) void gemm_b_k(const u16* __restrict__ A, long long sAb, int lda,
                                                  const u16* __restrict__ Bm, long long sBb, int ldb,
                                                  float* __restrict__ C, long long sCb, int ldc,
                                                  const float* __restrict__ bias,
                                                  u16* __restrict__ ZT,
                                                  int K, int tiles_n){
  __shared__ __align__(16) u16 As[128*64];
  __shared__ __align__(16) u16 Bs[128*64];
  const int b = blockIdx.y;
  const int bm = blockIdx.x / tiles_n, bn = blockIdx.x % tiles_n;
  const int tid = threadIdx.x, wave = tid>>6, lane = tid&63;
  const int wr = wave>>1, wc = wave&1;
  const u16* Ab = A  + (size_t)b*sAb + (size_t)(bm*128)*lda;
  const u16* Bb = Bm + (size_t)b*sBb + (size_t)(bn*128)*ldb;
  f32x4 acc[4][4];
  #pragma unroll
  for (int i=0;i<4;i++)
    #pragma unroll
    for (int j=0;j<4;j++) acc[i][j] = (f32x4){0.f,0.f,0.f,0.f};

  for (int k0 = 0; k0 < K; k0 += 64){
    __syncthreads();
    stage_tile(As, Ab + k0, lda, wave, lane);
    stage_tile(Bs, Bb + k0, ldb, wave, lane);
    __syncthreads();
    #pragma unroll
    for (int kk=0;kk<2;kk++){
      const int ko = kk*32 + ((lane>>4)<<3);
      bf16x8 a[4], bb[4];
      #pragma unroll
      for (int mi=0;mi<4;mi++) a[mi]  = frag_ld(As, wr*64 + mi*16 + (lane&15), ko);
      #pragma unroll
      for (int ni=0;ni<4;ni++) bb[ni] = frag_ld(Bs, wc*64 + ni*16 + (lane&15), ko);
      #pragma unroll
      for (int mi=0;mi<4;mi++)
        #pragma unroll
        for (int ni=0;ni<4;ni++)
          acc[mi][ni] = __builtin_amdgcn_mfma_f32_16x16x32_bf16(a[mi], bb[ni], acc[mi][ni], 0,0,0);
    }
  }
  const int m0 = bm*128, n0 = bn*128;
  if (EPI == 0){
    float* Cb = C + (size_t)b*sCb;
    #pragma unroll
    for (int mi=0;mi<4;mi++)
      #pragma unroll
      for (int ni=0;ni<4;ni++){
        const int r = m0 + wr*64 + mi*16 + ((lane>>4)<<2);
        const int c = n0 + wc*64 + ni*16 + (lane&15);
        const float bv = bias ? bias[c] : 0.f;
        #pragma unroll
        for (int j=0;j<4;j++)
          Cb[(size_t)(r+j)*ldc + c] = acc[mi][ni][j] + bv;
      }
  } else {
    #pragma unroll
    for (int mi=0;mi<4;mi++)
      #pragma unroll
      for (int ni=0;ni<4;ni++){
        const int l = m0 + wr*64 + mi*16 + ((lane>>4)<<2);   // global row (b*2048+m)
        const int bb2 = l >> 11, m = l & 2047;
        const int d = n0 + wc*64 + ni*16 + (lane&15);
        u16x4 w;
        #pragma unroll
        for (int j=0;j<4;j++) w[j] = f2bf(acc[mi][ni][j]);
        *reinterpret_cast<u16x4*>(ZT + ((size_t)bb2*DD + d)*LL + m) = w;
      }
  }
}

// ---------- host launch ----------
extern "C" void kernel_launch(void* const* d_in, const int* in_sizes, int n_in,
                              void* d_out, int out_size, void* d_ws, size_t ws_size,
                              hipStream_t stream) {
  const float* f1 = (const float*)d_in[0];
  const float* f2 = (const float*)d_in[1];
  const float* W1 = (const float*)d_in[2];
  const float* b1 = (const float*)d_in[3];
  const float* W2 = (const float*)d_in[4];
  const float* b2 = (const float*)d_in[5];
  float* out1 = (float*)d_out;
  float* out2 = out1 + (size_t)BB*LL*DD;

  // workspace layout (bytes); peak need ~136.3 MB
  char* ws = (char*)d_ws;
  u16* t1h = (u16*)(ws + 0);              // 16 MiB
  u16* t1l = (u16*)(ws + 16777216);       // 16 MiB; reused as ZT after sim GEMM
  u16* f2h = (u16*)(ws + 33554432);       // 16 MiB
  u16* f2l = (u16*)(ws + 50331648);       // 16 MiB; reused as f2T after sim GEMM
  u16* w2b = (u16*)(ws + 67108864);       // 2 MiB
  float* sim = (float*)(ws + 69206016);   // 64 MiB; attn bf16 written in place

  // 1. split f2 -> hi/lo bf16
  split_k<<<4096, 256, 0, stream>>>(f2, f2h, f2l, (BB*LL*DD)/4);
  // 2. W2 -> bf16 (hi only)
  split_k<<<1024, 256, 0, stream>>>(W2, w2b, nullptr, (DD*DD)/4);
  // 3. t1 = f1 @ W1^T + b1 (split-precision), write hi/lo
  gemm_t1_k<<<512, 256, 0, stream>>>(f1, W1, b1, t1h, t1l);
  // 4. sim[b] = t1[b] @ f2[b]^T (split-precision, f32)
  gemm_sim_k<<<dim3(256, BB), 256, 0, stream>>>(t1h, t1l, f2h, f2l, sim);
  // 5. softmax rows, write attn bf16 in place
  softmax_k<<<BB*LL, 256, 0, stream>>>(sim);
  // 6. f2T = transpose(f2_hi) into f2l region (f2_lo dead now)
  transpose_k<<<dim3(32, 64, BB), dim3(32, 8), 0, stream>>>(f2h, f2l);
  // 7. ZT = (t1 @ W2^T)^T bf16 into t1l region (t1_lo dead now)
  gemm_b_k<1><<<dim3(512, 1), 256, 0, stream>>>(t1h, 0, DD, w2b, 0, DD,
                                                nullptr, 0, 0, nullptr, t1l, DD, 8);
  // 8. attended_1 = attn @ f2   (A=attn bf16 with row stride 4096 elems, B=f2T)
  gemm_b_k<0><<<dim3(128, BB), 256, 0, stream>>>((const u16*)sim, (long long)LL*4096, 4096,
                                                 f2l, (long long)DD*LL, LL,
                                                 out1, (long long)LL*DD, DD,
                                                 nullptr, nullptr, LL, 8);
  // 9. attended_2 = attn @ Z + b2
  gemm_b_k<0><<<dim3(128, BB), 256, 0, stream>>>((const u16*)sim, (long long)LL*4096, 4096,
                                                 t1l, (long long)DD*LL, LL,
                                                 out2, (long long)LL*DD, DD,
                                                 b2, nullptr, LL, 8);
}

// Round 2
// 339.348 us; speedup vs baseline: 1.1275x; 1.1275x over previous
//
#include <hip/hip_runtime.h>
#include <stdint.h>

// Problem constants
#define BB 4
#define LL 2048
#define DD 1024

typedef __attribute__((ext_vector_type(4))) float f32x4;
typedef __attribute__((ext_vector_type(8))) __bf16 bf16x8;
typedef __attribute__((ext_vector_type(4))) unsigned short u16x4;
typedef unsigned short u16;

// ---------- bf16 helpers (manual RNE) ----------
__device__ __forceinline__ u16 f2bf(float x){
  unsigned u = __float_as_uint(x);
  u += 0x7FFFu + ((u >> 16) & 1u);
  return (u16)(u >> 16);
}
__device__ __forceinline__ float bf2f(u16 h){
  return __uint_as_float(((unsigned)h) << 16);
}

// ---------- async global->LDS staging (16B/lane) ----------
__device__ __forceinline__ void gload16(const u16* g, u16* l){
  __builtin_amdgcn_global_load_lds((const __attribute__((address_space(1))) unsigned*)g,
                                   (__attribute__((address_space(3))) unsigned*)l,
                                   16, 0, 0);
}

// stage a [128][64] bf16 tile from row-major src (ld elems) into linear LDS [128][64]
__device__ __forceinline__ void stage_tile(u16* lds, const u16* src, int ld, int wave, int lane){
  const int r0 = lane >> 3;          // 0..7 row within 8-row group
  const int ce = (lane & 7) << 3;    // elem col (8 bf16 = 16B chunks)
  #pragma unroll
  for (int j = 0; j < 4; ++j){
    const int rb = wave*32 + j*8;    // wave-uniform row base
    gload16(src + (size_t)(rb + r0)*ld + ce, lds + rb*64);
  }
}

__device__ __forceinline__ bf16x8 frag_ld(const u16* t, int row, int ko){
  return __builtin_bit_cast(bf16x8, *reinterpret_cast<const f32x4*>(t + row*64 + ko));
}

// ---------- kernel: f32 -> bf16 hi/lo split (lo may be null) ----------
__global__ void split_k(const float* __restrict__ src, u16* __restrict__ hi,
                        u16* __restrict__ lo, int n4){
  const int stride = gridDim.x * blockDim.x;
  for (int i = blockIdx.x*blockDim.x + threadIdx.x; i < n4; i += stride){
    f32x4 v = reinterpret_cast<const f32x4*>(src)[i];
    u16x4 h, l;
    #pragma unroll
    for (int j = 0; j < 4; ++j){
      u16 hb = f2bf(v[j]);
      h[j] = hb;
      l[j] = f2bf(v[j] - bf2f(hb));
    }
    reinterpret_cast<u16x4*>(hi)[i] = h;
    if (lo) reinterpret_cast<u16x4*>(lo)[i] = l;
  }
}

// ---------- split-precision 3-product GEMM (A,B pre-split hi/lo bf16, K-contig) ----------
// EPI=0: C = A@B^T f32 (ldc). EPI=1: hi/lo bf16 out (+bias per col), ldc.
template<int EPI>
__global__ __launch_bounds__(256,2) void gemm3_k(
    const u16* __restrict__ Ah_g, const u16* __restrict__ Al_g, long long sAb, int lda,
    const u16* __restrict__ Bh_g, const u16* __restrict__ Bl_g, long long sBb, int ldb,
    float* __restrict__ C, long long sCb, int ldc,
    const float* __restrict__ bias, u16* __restrict__ Oh, u16* __restrict__ Ol,
    int K, int tiles_n){
  __shared__ __align__(16) u16 Ah[128*64];
  __shared__ __align__(16) u16 Al[128*64];
  __shared__ __align__(16) u16 Bh[128*64];
  __shared__ __align__(16) u16 Bl[128*64];
  const int b = blockIdx.y;
  const int bm = blockIdx.x / tiles_n, bn = blockIdx.x % tiles_n;
  const int tid = threadIdx.x, wave = tid>>6, lane = tid&63;
  const int wr = wave>>1, wc = wave&1;
  const u16* A_h = Ah_g + (size_t)b*sAb + (size_t)(bm*128)*lda;
  const u16* A_l = Al_g + (size_t)b*sAb + (size_t)(bm*128)*lda;
  const u16* B_h = Bh_g + (size_t)b*sBb + (size_t)(bn*128)*ldb;
  const u16* B_l = Bl_g + (size_t)b*sBb + (size_t)(bn*128)*ldb;
  f32x4 acc[4][4];
  #pragma unroll
  for (int i=0;i<4;i++)
    #pragma unroll
    for (int j=0;j<4;j++) acc[i][j] = (f32x4){0.f,0.f,0.f,0.f};

  for (int k0 = 0; k0 < K; k0 += 64){
    __syncthreads();
    stage_tile(Ah, A_h + k0, lda, wave, lane);
    stage_tile(Al, A_l + k0, lda, wave, lane);
    stage_tile(Bh, B_h + k0, ldb, wave, lane);
    stage_tile(Bl, B_l + k0, ldb, wave, lane);
    __syncthreads();
    #pragma unroll
    for (int kk=0;kk<2;kk++){
      const int ko = kk*32 + ((lane>>4)<<3);
      bf16x8 ah[4], al[4], bh[4], bl[4];
      #pragma unroll
      for (int mi=0;mi<4;mi++){
        const int r = wr*64 + mi*16 + (lane&15);
        ah[mi] = frag_ld(Ah, r, ko);
        al[mi] = frag_ld(Al, r, ko);
      }
      #pragma unroll
      for (int ni=0;ni<4;ni++){
        const int r = wc*64 + ni*16 + (lane&15);
        bh[ni] = frag_ld(Bh, r, ko);
        bl[ni] = frag_ld(Bl, r, ko);
      }
      #pragma unroll
      for (int mi=0;mi<4;mi++)
        #pragma unroll
        for (int ni=0;ni<4;ni++){
          acc[mi][ni] = __builtin_amdgcn_mfma_f32_16x16x32_bf16(ah[mi], bh[ni], acc[mi][ni], 0,0,0);
          acc[mi][ni] = __builtin_amdgcn_mfma_f32_16x16x32_bf16(ah[mi], bl[ni], acc[mi][ni], 0,0,0);
          acc[mi][ni] = __builtin_amdgcn_mfma_f32_16x16x32_bf16(al[mi], bh[ni], acc[mi][ni], 0,0,0);
        }
    }
  }
  const int m0 = bm*128, n0 = bn*128;
  if (EPI == 0){
    float* Cb = C + (size_t)b*sCb;
    #pragma unroll
    for (int mi=0;mi<4;mi++)
      #pragma unroll
      for (int ni=0;ni<4;ni++){
        const int r = m0 + wr*64 + mi*16 + ((lane>>4)<<2);
        const int c = n0 + wc*64 + ni*16 + (lane&15);
        #pragma unroll
        for (int j=0;j<4;j++)
          Cb[(size_t)(r+j)*ldc + c] = acc[mi][ni][j];
      }
  } else {
    #pragma unroll
    for (int mi=0;mi<4;mi++)
      #pragma unroll
      for (int ni=0;ni<4;ni++){
        const int r = m0 + wr*64 + mi*16 + ((lane>>4)<<2);
        const int c = n0 + wc*64 + ni*16 + (lane&15);
        const float bv = bias[c];
        #pragma unroll
        for (int j=0;j<4;j++){
          const float x = acc[mi][ni][j] + bv;
          const u16 hb = f2bf(x);
          Oh[(size_t)(r+j)*ldc + c] = hb;
          Ol[(size_t)(r+j)*ldc + c] = f2bf(x - bf2f(hb));
        }
      }
  }
}

// ---------- kernel: row softmax f32->bf16 in place (attn at row byte offset row*8192) ----------
__global__ __launch_bounds__(256) void softmax_k(float* __restrict__ sim){
  const int row = blockIdx.x;            // b*2048 + l
  float* p = sim + (size_t)row * LL;
  const int tid = threadIdx.x, wave = tid>>6, lane = tid&63;
  f32x4 x0 = reinterpret_cast<const f32x4*>(p)[tid];
  f32x4 x1 = reinterpret_cast<const f32x4*>(p)[tid + 256];
  float mx = fmaxf(fmaxf(fmaxf(x0[0],x0[1]), fmaxf(x0[2],x0[3])),
                   fmaxf(fmaxf(x1[0],x1[1]), fmaxf(x1[2],x1[3])));
  #pragma unroll
  for (int o = 32; o; o >>= 1) mx = fmaxf(mx, __shfl_xor(mx, o, 64));
  __shared__ float red[8];
  if (lane == 0) red[wave] = mx;
  __syncthreads();
  mx = fmaxf(fmaxf(red[0], red[1]), fmaxf(red[2], red[3]));
  float e0[4], e1[4], s = 0.f;
  #pragma unroll
  for (int j=0;j<4;j++){ e0[j] = __expf(x0[j]-mx); s += e0[j]; }
  #pragma unroll
  for (int j=0;j<4;j++){ e1[j] = __expf(x1[j]-mx); s += e1[j]; }
  #pragma unroll
  for (int o = 32; o; o >>= 1) s += __shfl_xor(s, o, 64);
  if (lane == 0) red[4+wave] = s;
  __syncthreads();
  s = (red[4]+red[5]) + (red[6]+red[7]);
  const float inv = 1.0f / s;
  u16* ob = reinterpret_cast<u16*>(p);   // row base byte = row*8192
  u16x4 w0, w1;
  #pragma unroll
  for (int j=0;j<4;j++){ w0[j] = f2bf(e0[j]*inv); w1[j] = f2bf(e1[j]*inv); }
  reinterpret_cast<u16x4*>(ob)[tid]       = w0;
  reinterpret_cast<u16x4*>(ob)[tid + 256] = w1;
}

// ---------- kernel: bf16 transpose per batch [2048][1024] -> [1024][2048] ----------
__global__ void transpose_k(const u16* __restrict__ in, u16* __restrict__ out){
  __shared__ u16 t[32][33];
  const int b = blockIdx.z;
  const int e0 = blockIdx.x*32, m0 = blockIdx.y*32;
  const u16* src = in  + (size_t)b*LL*DD;
  u16* dst       = out + (size_t)b*DD*LL;
  for (int j = threadIdx.y; j < 32; j += 8)
    t[j][threadIdx.x] = src[(size_t)(m0+j)*DD + e0 + threadIdx.x];
  __syncthreads();
  for (int j = threadIdx.y; j < 32; j += 8)
    dst[(size_t)(e0+j)*LL + m0 + threadIdx.x] = t[threadIdx.x][j];
}

// ---------- generic bf16 1-product GEMM (A [.,K] K-contig, B "B^T" [N][K] K-contig) ----------
// EPI=0: C f32 (+optional bias per col). EPI=1: scatter-transposed bf16 ZT[b][d][m].
template<int EPI>
__global__ __launch_bounds__(256,2) void gemm_b_k(const u16* __restrict__ A, long long sAb, int lda,
                                                  const u16* __restrict__ Bm, long long sBb, int ldb,
                                                  float* __restrict__ C, long long sCb, int ldc,
                                                  const float* __restrict__ bias,
                                                  u16* __restrict__ ZT,
                                                  int K, int tiles_n){
  __shared__ __align__(16) u16 As[128*64];
  __shared__ __align__(16) u16 Bs[128*64];
  const int b = blockIdx.y;
  const int bm = blockIdx.x / tiles_n, bn = blockIdx.x % tiles_n;
  const int tid = threadIdx.x, wave = tid>>6, lane = tid&63;
  const int wr = wave>>1, wc = wave&1;
  const u16* Ab = A  + (size_t)b*sAb + (size_t)(bm*128)*lda;
  const u16* Bb = Bm + (size_t)b*sBb + (size_t)(bn*128)*ldb;
  f32x4 acc[4][4];
  #pragma unroll
  for (int i=0;i<4;i++)
    #pragma unroll
    for (int j=0;j<4;j++) acc[i][j] = (f32x4){0.f,0.f,0.f,0.f};

  for (int k0 = 0; k0 < K; k0 += 64){
    __syncthreads();
    stage_tile(As, Ab + k0, lda, wave, lane);
    stage_tile(Bs, Bb + k0, ldb, wave, lane);
    __syncthreads();
    #pragma unroll
    for (int kk=0;kk<2;kk++){
      const int ko = kk*32 + ((lane>>4)<<3);
      bf16x8 a[4], bb[4];
      #pragma unroll
      for (int mi=0;mi<4;mi++) a[mi]  = frag_ld(As, wr*64 + mi*16 + (lane&15), ko);
      #pragma unroll
      for (int ni=0;ni<4;ni++) bb[ni] = frag_ld(Bs, wc*64 + ni*16 + (lane&15), ko);
      #pragma unroll
      for (int mi=0;mi<4;mi++)
        #pragma unroll
        for (int ni=0;ni<4;ni++)
          acc[mi][ni] = __builtin_amdgcn_mfma_f32_16x16x32_bf16(a[mi], bb[ni], acc[mi][ni], 0,0,0);
    }
  }
  const int m0 = bm*128, n0 = bn*128;
  if (EPI == 0){
    float* Cb = C + (size_t)b*sCb;
    #pragma unroll
    for (int mi=0;mi<4;mi++)
      #pragma unroll
      for (int ni=0;ni<4;ni++){
        const int r = m0 + wr*64 + mi*16 + ((lane>>4)<<2);
        const int c = n0 + wc*64 + ni*16 + (lane&15);
        const float bv = bias ? bias[c] : 0.f;
        #pragma unroll
        for (int j=0;j<4;j++)
          Cb[(size_t)(r+j)*ldc + c] = acc[mi][ni][j] + bv;
      }
  } else {
    #pragma unroll
    for (int mi=0;mi<4;mi++)
      #pragma unroll
      for (int ni=0;ni<4;ni++){
        const int l = m0 + wr*64 + mi*16 + ((lane>>4)<<2);   // global row (b*2048+m)
        const int bb2 = l >> 11, m = l & 2047;
        const int d = n0 + wc*64 + ni*16 + (lane&15);
        u16x4 w;
        #pragma unroll
        for (int j=0;j<4;j++) w[j] = f2bf(acc[mi][ni][j]);
        *reinterpret_cast<u16x4*>(ZT + ((size_t)bb2*DD + d)*LL + m) = w;
      }
  }
}

// ---------- host launch ----------
extern "C" void kernel_launch(void* const* d_in, const int* in_sizes, int n_in,
                              void* d_out, int out_size, void* d_ws, size_t ws_size,
                              hipStream_t stream) {
  const float* f1 = (const float*)d_in[0];
  const float* f2 = (const float*)d_in[1];
  const float* W1 = (const float*)d_in[2];
  const float* b1 = (const float*)d_in[3];
  const float* W2 = (const float*)d_in[4];
  const float* b2 = (const float*)d_in[5];
  float* out1 = (float*)d_out;
  float* out2 = out1 + (size_t)BB*LL*DD;

  // workspace layout (bytes); peak ~130 MB (same as round 1)
  char* ws = (char*)d_ws;
  u16* t1h = (u16*)(ws + 0);              // 16 MiB
  u16* t1l = (u16*)(ws + 16777216);       // 16 MiB; reused as ZT after sim GEMM
  u16* f2h = (u16*)(ws + 33554432);       // 16 MiB
  u16* f2l = (u16*)(ws + 50331648);       // 16 MiB; reused as f2T after sim GEMM
  u16* w2b = (u16*)(ws + 67108864);       // 2 MiB
  float* sim = (float*)(ws + 69206016);   // 64 MiB; attn bf16 written in place
  // f1h/f1l/w1h/w1l alias the sim region (dead before sim GEMM runs)
  u16* f1h = (u16*)(ws + 69206016);                 // 16 MiB
  u16* f1l = (u16*)(ws + 69206016 + 16777216);      // 16 MiB
  u16* w1h = (u16*)(ws + 69206016 + 33554432);      // 2 MiB
  u16* w1l = (u16*)(ws + 69206016 + 35651584);      // 2 MiB

  // 1. splits: f2, f1 -> hi/lo; W1 -> hi/lo; W2 -> bf16 hi only
  split_k<<<4096, 256, 0, stream>>>(f2, f2h, f2l, (BB*LL*DD)/4);
  split_k<<<4096, 256, 0, stream>>>(f1, f1h, f1l, (BB*LL*DD)/4);
  split_k<<<1024, 256, 0, stream>>>(W1, w1h, w1l, (DD*DD)/4);
  split_k<<<1024, 256, 0, stream>>>(W2, w2b, nullptr, (DD*DD)/4);
  // 2. t1 = f1 @ W1^T + b1 (split 3-product), write t1 hi/lo
  gemm3_k<1><<<dim3(512, 1), 256, 0, stream>>>(f1h, f1l, 0, DD,
                                               w1h, w1l, 0, DD,
                                               nullptr, 0, DD,
                                               b1, t1h, t1l, DD, 8);
  // 3. sim[b] = t1[b] @ f2[b]^T (split 3-product, f32) — overwrites f1/W1 splits
  gemm3_k<0><<<dim3(256, BB), 256, 0, stream>>>(t1h, t1l, (long long)LL*DD, DD,
                                                f2h, f2l, (long long)LL*DD, DD,
                                                sim, (long long)LL*LL, LL,
                                                nullptr, nullptr, nullptr, DD, 16);
  // 4. softmax rows, write attn bf16 in place
  softmax_k<<<BB*LL, 256, 0, stream>>>(sim);
  // 5. f2T = transpose(f2_hi) into f2l region (f2_lo dead now)
  transpose_k<<<dim3(32, 64, BB), dim3(32, 8), 0, stream>>>(f2h, f2l);
  // 6. ZT = (t1 @ W2^T)^T bf16 into t1l region (t1_lo dead now)
  gemm_b_k<1><<<dim3(512, 1), 256, 0, stream>>>(t1h, 0, DD, w2b, 0, DD,
                                                nullptr, 0, 0, nullptr, t1l, DD, 8);
  // 7. attended_1 = attn @ f2   (A=attn bf16 with row stride 4096 elems, B=f2T)
  gemm_b_k<0><<<dim3(128, BB), 256, 0, stream>>>((const u16*)sim, (long long)LL*4096, 4096,
                                                 f2l, (long long)DD*LL, LL,
                                                 out1, (long long)LL*DD, DD,
                                                 nullptr, nullptr, LL, 8);
  // 8. attended_2 = attn @ Z + b2
  gemm_b_k<0><<<dim3(128, BB), 256, 0, stream>>>((const u16*)sim, (long long)LL*4096, 4096,
                                                 t1l, (long long)DD*LL, LL,
                                                 out2, (long long)LL*DD, DD,
                                                 b2, nullptr, LL, 8);
}

// Round 3
// 284.542 us; speedup vs baseline: 1.3447x; 1.1926x over previous
//
#include <hip/hip_runtime.h>
#include <stdint.h>

// Problem constants
#define BB 4
#define LL 2048
#define DD 1024

typedef __attribute__((ext_vector_type(4))) float f32x4;
typedef __attribute__((ext_vector_type(8))) __bf16 bf16x8;
typedef __attribute__((ext_vector_type(4))) unsigned short u16x4;
typedef unsigned short u16;

// ---------- bf16 helpers (manual RNE) ----------
__device__ __forceinline__ u16 f2bf(float x){
  unsigned u = __float_as_uint(x);
  u += 0x7FFFu + ((u >> 16) & 1u);
  return (u16)(u >> 16);
}
__device__ __forceinline__ float bf2f(u16 h){
  return __uint_as_float(((unsigned)h) << 16);
}

// ---------- async global->LDS staging (16B/lane) ----------
__device__ __forceinline__ void gload16(const u16* g, u16* l){
  __builtin_amdgcn_global_load_lds((const __attribute__((address_space(1))) unsigned*)g,
                                   (__attribute__((address_space(3))) unsigned*)l,
                                   16, 0, 0);
}

// XCD-aware chunked block swizzle (requires nwg % 8 == 0; all our grids comply)
__device__ __forceinline__ int xcd_swz(int bx, int nwg){
  return (bx & 7) * (nwg >> 3) + (bx >> 3);
}

// stage a [128][64] bf16 tile, 8 waves, XOR-swizzled:
// LDS dest is LINEAR (global_load_lds requirement); the SOURCE col is
// pre-swizzled so that phys slot s holds logical slot s ^ (row&7).
__device__ __forceinline__ void stage_tile8(u16* lds, const u16* src, int ld, int wave, int lane){
  const int r0 = lane >> 3;                       // row within 8-row group
  const int cs = (((lane & 7) ^ r0) << 3);        // swizzled source col (elems)
  #pragma unroll
  for (int j = 0; j < 2; ++j){
    const int rb = wave*16 + j*8;                 // wave-uniform row base (mult of 8)
    gload16(src + (size_t)(rb + r0)*ld + cs, lds + rb*64);
  }
}

// swizzled fragment read: logical (row, ko) lives at phys col ko ^ ((row&7)<<3)
__device__ __forceinline__ bf16x8 frag_ld(const u16* t, int row, int ko){
  return __builtin_bit_cast(bf16x8,
    *reinterpret_cast<const f32x4*>(t + row*64 + (ko ^ ((row & 7) << 3))));
}

// ---------- kernel: f32 -> bf16 hi/lo split (lo may be null) ----------
__global__ void split_k(const float* __restrict__ src, u16* __restrict__ hi,
                        u16* __restrict__ lo, int n4){
  const int stride = gridDim.x * blockDim.x;
  for (int i = blockIdx.x*blockDim.x + threadIdx.x; i < n4; i += stride){
    f32x4 v = reinterpret_cast<const f32x4*>(src)[i];
    u16x4 h, l;
    #pragma unroll
    for (int j = 0; j < 4; ++j){
      u16 hb = f2bf(v[j]);
      h[j] = hb;
      l[j] = f2bf(v[j] - bf2f(hb));
    }
    reinterpret_cast<u16x4*>(hi)[i] = h;
    if (lo) reinterpret_cast<u16x4*>(lo)[i] = l;
  }
}

// ---------- split-precision 3-product GEMM, 8 waves, swizzled LDS ----------
// per-wave output 64x32: wr=wave>>2 (2), wc=wave&3 (4). acc[4][2].
// EPI=0: C = A@B^T f32. EPI=1: hi/lo bf16 out (+bias per col).
template<int EPI>
__global__ __launch_bounds__(512,4) void gemm3_k(
    const u16* __restrict__ Ah_g, const u16* __restrict__ Al_g, long long sAb, int lda,
    const u16* __restrict__ Bh_g, const u16* __restrict__ Bl_g, long long sBb, int ldb,
    float* __restrict__ C, long long sCb, int ldc,
    const float* __restrict__ bias, u16* __restrict__ Oh, u16* __restrict__ Ol,
    int K, int tn_sh){
  __shared__ __align__(16) u16 Ah[128*64];
  __shared__ __align__(16) u16 Al[128*64];
  __shared__ __align__(16) u16 Bh[128*64];
  __shared__ __align__(16) u16 Bl[128*64];
  const int b = blockIdx.y;
  const int bx = xcd_swz(blockIdx.x, gridDim.x);
  const int bm = bx >> tn_sh, bn = bx & ((1 << tn_sh) - 1);
  const int tid = threadIdx.x, wave = tid>>6, lane = tid&63;
  const int wr = wave>>2, wc = wave&3;
  const u16* A_h = Ah_g + (size_t)b*sAb + (size_t)(bm*128)*lda;
  const u16* A_l = Al_g + (size_t)b*sAb + (size_t)(bm*128)*lda;
  const u16* B_h = Bh_g + (size_t)b*sBb + (size_t)(bn*128)*ldb;
  const u16* B_l = Bl_g + (size_t)b*sBb + (size_t)(bn*128)*ldb;
  f32x4 acc[4][2];
  #pragma unroll
  for (int i=0;i<4;i++)
    #pragma unroll
    for (int j=0;j<2;j++) acc[i][j] = (f32x4){0.f,0.f,0.f,0.f};

  for (int k0 = 0; k0 < K; k0 += 64){
    __syncthreads();
    stage_tile8(Ah, A_h + k0, lda, wave, lane);
    stage_tile8(Al, A_l + k0, lda, wave, lane);
    stage_tile8(Bh, B_h + k0, ldb, wave, lane);
    stage_tile8(Bl, B_l + k0, ldb, wave, lane);
    __syncthreads();
    #pragma unroll
    for (int kk=0;kk<2;kk++){
      const int ko = kk*32 + ((lane>>4)<<3);
      bf16x8 ah[4], al[4], bh[2], bl[2];
      #pragma unroll
      for (int mi=0;mi<4;mi++){
        const int r = wr*64 + mi*16 + (lane&15);
        ah[mi] = frag_ld(Ah, r, ko);
        al[mi] = frag_ld(Al, r, ko);
      }
      #pragma unroll
      for (int ni=0;ni<2;ni++){
        const int r = wc*32 + ni*16 + (lane&15);
        bh[ni] = frag_ld(Bh, r, ko);
        bl[ni] = frag_ld(Bl, r, ko);
      }
      #pragma unroll
      for (int mi=0;mi<4;mi++)
        #pragma unroll
        for (int ni=0;ni<2;ni++){
          acc[mi][ni] = __builtin_amdgcn_mfma_f32_16x16x32_bf16(ah[mi], bh[ni], acc[mi][ni], 0,0,0);
          acc[mi][ni] = __builtin_amdgcn_mfma_f32_16x16x32_bf16(ah[mi], bl[ni], acc[mi][ni], 0,0,0);
          acc[mi][ni] = __builtin_amdgcn_mfma_f32_16x16x32_bf16(al[mi], bh[ni], acc[mi][ni], 0,0,0);
        }
    }
  }
  const int m0 = bm*128, n0 = bn*128;
  if (EPI == 0){
    float* Cb = C + (size_t)b*sCb;
    #pragma unroll
    for (int mi=0;mi<4;mi++)
      #pragma unroll
      for (int ni=0;ni<2;ni++){
        const int r = m0 + wr*64 + mi*16 + ((lane>>4)<<2);
        const int c = n0 + wc*32 + ni*16 + (lane&15);
        #pragma unroll
        for (int j=0;j<4;j++)
          Cb[(size_t)(r+j)*ldc + c] = acc[mi][ni][j];
      }
  } else {
    #pragma unroll
    for (int mi=0;mi<4;mi++)
      #pragma unroll
      for (int ni=0;ni<2;ni++){
        const int r = m0 + wr*64 + mi*16 + ((lane>>4)<<2);
        const int c = n0 + wc*32 + ni*16 + (lane&15);
        const float bv = bias[c];
        #pragma unroll
        for (int j=0;j<4;j++){
          const float x = acc[mi][ni][j] + bv;
          const u16 hb = f2bf(x);
          Oh[(size_t)(r+j)*ldc + c] = hb;
          Ol[(size_t)(r+j)*ldc + c] = f2bf(x - bf2f(hb));
        }
      }
  }
}

// ---------- kernel: row softmax f32->bf16 in place ----------
__global__ __launch_bounds__(256) void softmax_k(float* __restrict__ sim){
  const int row = blockIdx.x;            // b*2048 + l
  float* p = sim + (size_t)row * LL;
  const int tid = threadIdx.x, wave = tid>>6, lane = tid&63;
  f32x4 x0 = reinterpret_cast<const f32x4*>(p)[tid];
  f32x4 x1 = reinterpret_cast<const f32x4*>(p)[tid + 256];
  float mx = fmaxf(fmaxf(fmaxf(x0[0],x0[1]), fmaxf(x0[2],x0[3])),
                   fmaxf(fmaxf(x1[0],x1[1]), fmaxf(x1[2],x1[3])));
  #pragma unroll
  for (int o = 32; o; o >>= 1) mx = fmaxf(mx, __shfl_xor(mx, o, 64));
  __shared__ float red[8];
  if (lane == 0) red[wave] = mx;
  __syncthreads();
  mx = fmaxf(fmaxf(red[0], red[1]), fmaxf(red[2], red[3]));
  float e0[4], e1[4], s = 0.f;
  #pragma unroll
  for (int j=0;j<4;j++){ e0[j] = __expf(x0[j]-mx); s += e0[j]; }
  #pragma unroll
  for (int j=0;j<4;j++){ e1[j] = __expf(x1[j]-mx); s += e1[j]; }
  #pragma unroll
  for (int o = 32; o; o >>= 1) s += __shfl_xor(s, o, 64);
  if (lane == 0) red[4+wave] = s;
  __syncthreads();
  s = (red[4]+red[5]) + (red[6]+red[7]);
  const float inv = 1.0f / s;
  u16* ob = reinterpret_cast<u16*>(p);
  u16x4 w0, w1;
  #pragma unroll
  for (int j=0;j<4;j++){ w0[j] = f2bf(e0[j]*inv); w1[j] = f2bf(e1[j]*inv); }
  reinterpret_cast<u16x4*>(ob)[tid]       = w0;
  reinterpret_cast<u16x4*>(ob)[tid + 256] = w1;
}

// ---------- kernel: bf16 transpose per batch [2048][1024] -> [1024][2048] ----------
__global__ void transpose_k(const u16* __restrict__ in, u16* __restrict__ out){
  __shared__ u16 t[32][33];
  const int b = blockIdx.z;
  const int e0 = blockIdx.x*32, m0 = blockIdx.y*32;
  const u16* src = in  + (size_t)b*LL*DD;
  u16* dst       = out + (size_t)b*DD*LL;
  for (int j = threadIdx.y; j < 32; j += 8)
    t[j][threadIdx.x] = src[(size_t)(m0+j)*DD + e0 + threadIdx.x];
  __syncthreads();
  for (int j = threadIdx.y; j < 32; j += 8)
    dst[(size_t)(e0+j)*LL + m0 + threadIdx.x] = t[threadIdx.x][j];
}

// ---------- kernel: ZT = (t1 @ W2^T)^T bf16, 8 waves, swizzled ----------
// M=8192 rows (b*2048+m), N=1024 (d). grid 512 blocks: bm=bx>>3, bn=bx&7.
__global__ __launch_bounds__(512,4) void gemm_zt_k(const u16* __restrict__ t1h,
                                                   const u16* __restrict__ w2b,
                                                   u16* __restrict__ ZT){
  __shared__ __align__(16) u16 As[128*64];
  __shared__ __align__(16) u16 Bs[128*64];
  const int bx = xcd_swz(blockIdx.x, gridDim.x);
  const int bm = bx >> 3, bn = bx & 7;
  const int tid = threadIdx.x, wave = tid>>6, lane = tid&63;
  const int wr = wave>>2, wc = wave&3;
  const u16* Ab = t1h + (size_t)(bm*128)*DD;
  const u16* Bb = w2b + (size_t)(bn*128)*DD;
  f32x4 acc[4][2];
  #pragma unroll
  for (int i=0;i<4;i++)
    #pragma unroll
    for (int j=0;j<2;j++) acc[i][j] = (f32x4){0.f,0.f,0.f,0.f};

  for (int k0 = 0; k0 < DD; k0 += 64){
    __syncthreads();
    stage_tile8(As, Ab + k0, DD, wave, lane);
    stage_tile8(Bs, Bb + k0, DD, wave, lane);
    __syncthreads();
    #pragma unroll
    for (int kk=0;kk<2;kk++){
      const int ko = kk*32 + ((lane>>4)<<3);
      bf16x8 a[4], bb[2];
      #pragma unroll
      for (int mi=0;mi<4;mi++) a[mi]  = frag_ld(As, wr*64 + mi*16 + (lane&15), ko);
      #pragma unroll
      for (int ni=0;ni<2;ni++) bb[ni] = frag_ld(Bs, wc*32 + ni*16 + (lane&15), ko);
      #pragma unroll
      for (int mi=0;mi<4;mi++)
        #pragma unroll
        for (int ni=0;ni<2;ni++)
          acc[mi][ni] = __builtin_amdgcn_mfma_f32_16x16x32_bf16(a[mi], bb[ni], acc[mi][ni], 0,0,0);
    }
  }
  #pragma unroll
  for (int mi=0;mi<4;mi++)
    #pragma unroll
    for (int ni=0;ni<2;ni++){
      const int l = bm*128 + wr*64 + mi*16 + ((lane>>4)<<2);  // global row (b*2048+m)
      const int b2i = l >> 11, m = l & 2047;
      const int d = bn*128 + wc*32 + ni*16 + (lane&15);
      u16x4 w;
      #pragma unroll
      for (int j=0;j<4;j++) w[j] = f2bf(acc[mi][ni][j]);
      *reinterpret_cast<u16x4*>(ZT + ((size_t)b2i*DD + d)*LL + m) = w;
    }
}

// ---------- kernel: merged PV GEMM — out1 = attn@f2, out2 = attn@Z + b2 ----------
// A = attn bf16 [b][2048] rows at stride 4096 elems. B per bn: bn<8 -> f2T, else ZT
// (both [b][1024][2048], ld=LL). grid (256, BB): bm=bx>>4, bn=bx&15. K=2048.
__global__ __launch_bounds__(512,4) void gemm_pv_k(const u16* __restrict__ attn,
                                                   const u16* __restrict__ f2T,
                                                   const u16* __restrict__ ZT,
                                                   float* __restrict__ out1,
                                                   float* __restrict__ out2,
                                                   const float* __restrict__ b2){
  __shared__ __align__(16) u16 As[128*64];
  __shared__ __align__(16) u16 Bs[128*64];
  const int b = blockIdx.y;
  const int bx = xcd_swz(blockIdx.x, gridDim.x);
  const int bm = bx >> 4, bn = bx & 15;
  const int tid = threadIdx.x, wave = tid>>6, lane = tid&63;
  const int wr = wave>>2, wc = wave&3;
  const u16* Ab = attn + (size_t)b*LL*4096 + (size_t)(bm*128)*4096;
  const u16* Bbase = (bn < 8) ? f2T : ZT;
  const int d0 = (bn & 7) * 128;
  const u16* Bb = Bbase + (size_t)b*DD*LL + (size_t)d0*LL;
  f32x4 acc[4][2];
  #pragma unroll
  for (int i=0;i<4;i++)
    #pragma unroll
    for (int j=0;j<2;j++) acc[i][j] = (f32x4){0.f,0.f,0.f,0.f};

  for (int k0 = 0; k0 < LL; k0 += 64){
    __syncthreads();
    stage_tile8(As, Ab + k0, 4096, wave, lane);
    stage_tile8(Bs, Bb + k0, LL, wave, lane);
    __syncthreads();
    #pragma unroll
    for (int kk=0;kk<2;kk++){
      const int ko = kk*32 + ((lane>>4)<<3);
      bf16x8 a[4], bb[2];
      #pragma unroll
      for (int mi=0;mi<4;mi++) a[mi]  = frag_ld(As, wr*64 + mi*16 + (lane&15), ko);
      #pragma unroll
      for (int ni=0;ni<2;ni++) bb[ni] = frag_ld(Bs, wc*32 + ni*16 + (lane&15), ko);
      #pragma unroll
      for (int mi=0;mi<4;mi++)
        #pragma unroll
        for (int ni=0;ni<2;ni++)
          acc[mi][ni] = __builtin_amdgcn_mfma_f32_16x16x32_bf16(a[mi], bb[ni], acc[mi][ni], 0,0,0);
    }
  }
  float* O = ((bn < 8) ? out1 : out2) + (size_t)b*LL*DD;
  const bool has_bias = (bn >= 8);
  #pragma unroll
  for (int mi=0;mi<4;mi++)
    #pragma unroll
    for (int ni=0;ni<2;ni++){
      const int r = bm*128 + wr*64 + mi*16 + ((lane>>4)<<2);
      const int c = d0 + wc*32 + ni*16 + (lane&15);
      const float bv = has_bias ? b2[c] : 0.f;
      #pragma unroll
      for (int j=0;j<4;j++)
        O[(size_t)(r+j)*DD + c] = acc[mi][ni][j] + bv;
    }
}

// ---------- host launch ----------
extern "C" void kernel_launch(void* const* d_in, const int* in_sizes, int n_in,
                              void* d_out, int out_size, void* d_ws, size_t ws_size,
                              hipStream_t stream) {
  const float* f1 = (const float*)d_in[0];
  const float* f2 = (const float*)d_in[1];
  const float* W1 = (const float*)d_in[2];
  const float* b1 = (const float*)d_in[3];
  const float* W2 = (const float*)d_in[4];
  const float* b2 = (const float*)d_in[5];
  float* out1 = (float*)d_out;
  float* out2 = out1 + (size_t)BB*LL*DD;

  // workspace layout (bytes); peak ~130 MB
  char* ws = (char*)d_ws;
  u16* t1h = (u16*)(ws + 0);              // 16 MiB
  u16* t1l = (u16*)(ws + 16777216);       // 16 MiB; reused as ZT after sim GEMM
  u16* f2h = (u16*)(ws + 33554432);       // 16 MiB
  u16* f2l = (u16*)(ws + 50331648);       // 16 MiB; reused as f2T after sim GEMM
  u16* w2b = (u16*)(ws + 67108864);       // 2 MiB
  float* sim = (float*)(ws + 69206016);   // 64 MiB; attn bf16 written in place
  // f1h/f1l/w1h/w1l alias the sim region (dead before sim GEMM runs)
  u16* f1h = (u16*)(ws + 69206016);                 // 16 MiB
  u16* f1l = (u16*)(ws + 69206016 + 16777216);      // 16 MiB
  u16* w1h = (u16*)(ws + 69206016 + 33554432);      // 2 MiB
  u16* w1l = (u16*)(ws + 69206016 + 35651584);      // 2 MiB

  // 1. splits
  split_k<<<4096, 256, 0, stream>>>(f2, f2h, f2l, (BB*LL*DD)/4);
  split_k<<<4096, 256, 0, stream>>>(f1, f1h, f1l, (BB*LL*DD)/4);
  split_k<<<1024, 256, 0, stream>>>(W1, w1h, w1l, (DD*DD)/4);
  split_k<<<1024, 256, 0, stream>>>(W2, w2b, nullptr, (DD*DD)/4);
  // 2. t1 = f1 @ W1^T + b1 (split 3-product), write t1 hi/lo. tiles 64x8.
  gemm3_k<1><<<dim3(512, 1), 512, 0, stream>>>(f1h, f1l, 0, DD,
                                               w1h, w1l, 0, DD,
                                               nullptr, 0, DD,
                                               b1, t1h, t1l, DD, 3);
  // 3. sim[b] = t1[b] @ f2[b]^T (split 3-product, f32). tiles 16x16 per batch.
  gemm3_k<0><<<dim3(256, BB), 512, 0, stream>>>(t1h, t1l, (long long)LL*DD, DD,
                                                f2h, f2l, (long long)LL*DD, DD,
                                                sim, (long long)LL*LL, LL,
                                                nullptr, nullptr, nullptr, DD, 4);
  // 4. softmax rows, write attn bf16 in place
  softmax_k<<<BB*LL, 256, 0, stream>>>(sim);
  // 5. f2T = transpose(f2_hi) into f2l region (f2_lo dead now)
  transpose_k<<<dim3(32, 64, BB), dim3(32, 8), 0, stream>>>(f2h, f2l);
  // 6. ZT = (t1 @ W2^T)^T bf16 into t1l region (t1_lo dead now)
  gemm_zt_k<<<dim3(512, 1), 512, 0, stream>>>(t1h, w2b, t1l);
  // 7. merged PV: out1 = attn@f2, out2 = attn@Z + b2
  gemm_pv_k<<<dim3(256, BB), 512, 0, stream>>>((const u16*)sim, f2l, t1l,
                                               out1, out2, b2);
}

// Round 4
// 221.187 us; speedup vs baseline: 1.7299x; 1.2864x over previous
//
#include <hip/hip_runtime.h>
#include <stdint.h>

// Problem constants
#define BB 4
#define LL 2048
#define DD 1024

typedef __attribute__((ext_vector_type(4))) float f32x4;
typedef __attribute__((ext_vector_type(8))) _Float16 f16x8;
typedef __attribute__((ext_vector_type(4))) unsigned short u16x4;
typedef unsigned short u16;

// ---------- fp16 helper (RNE via hardware cvt) ----------
__device__ __forceinline__ u16 f2h(float x){
  return __builtin_bit_cast(u16, (_Float16)x);
}

// ---------- async global->LDS staging (16B/lane) ----------
__device__ __forceinline__ void gload16(const u16* g, u16* l){
  __builtin_amdgcn_global_load_lds((const __attribute__((address_space(1))) unsigned*)g,
                                   (__attribute__((address_space(3))) unsigned*)l,
                                   16, 0, 0);
}

// XCD-aware chunked block swizzle (requires nwg % 8 == 0; all our grids comply)
__device__ __forceinline__ int xcd_swz(int bx, int nwg){
  return (bx & 7) * (nwg >> 3) + (bx >> 3);
}

// stage a [128][64] fp16 tile, 8 waves, XOR-swizzled:
// LDS dest LINEAR (global_load_lds requirement); SOURCE col pre-swizzled so
// phys 16B slot s of row r holds logical slot s ^ (r&7).
__device__ __forceinline__ void stage_tile8(u16* lds, const u16* src, int ld, int wave, int lane){
  const int r0 = lane >> 3;                       // row within 8-row group
  const int cs = (((lane & 7) ^ r0) << 3);        // swizzled source col (elems)
  #pragma unroll
  for (int j = 0; j < 2; ++j){
    const int rb = wave*16 + j*8;                 // wave-uniform row base (mult of 8)
    gload16(src + (size_t)(rb + r0)*ld + cs, lds + rb*64);
  }
}

// swizzled fragment read: logical (row, ko) lives at phys col ko ^ ((row&7)<<3)
__device__ __forceinline__ f16x8 frag_ld(const u16* t, int row, int ko){
  return __builtin_bit_cast(f16x8,
    *reinterpret_cast<const f32x4*>(t + row*64 + (ko ^ ((row & 7) << 3))));
}

// ---------- kernel: f32 -> fp16 cast ----------
__global__ void cast_k(const float* __restrict__ src, u16* __restrict__ dst, int n4){
  const int stride = gridDim.x * blockDim.x;
  for (int i = blockIdx.x*blockDim.x + threadIdx.x; i < n4; i += stride){
    f32x4 v = reinterpret_cast<const f32x4*>(src)[i];
    u16x4 h;
    #pragma unroll
    for (int j = 0; j < 4; ++j) h[j] = f2h(v[j]);
    reinterpret_cast<u16x4*>(dst)[i] = h;
  }
}

// ---------- fp16 GEMM (A [.,K] K-contig, B "B^T" [N][K] K-contig), 8 waves ----------
// per-wave output 64x32: wr=wave>>2, wc=wave&3. acc[4][2].
// EPI=0: C = A@B^T f32. EPI=1: fp16 out (+bias per col).
template<int EPI>
__global__ __launch_bounds__(512,4) void gemm_h_k(
    const u16* __restrict__ A_g, long long sAb, int lda,
    const u16* __restrict__ B_g, long long sBb, int ldb,
    float* __restrict__ C, long long sCb, int ldc,
    const float* __restrict__ bias, u16* __restrict__ Oh,
    int K, int tn_sh){
  __shared__ __align__(16) u16 As[128*64];
  __shared__ __align__(16) u16 Bs[128*64];
  const int b = blockIdx.y;
  const int bx = xcd_swz(blockIdx.x, gridDim.x);
  const int bm = bx >> tn_sh, bn = bx & ((1 << tn_sh) - 1);
  const int tid = threadIdx.x, wave = tid>>6, lane = tid&63;
  const int wr = wave>>2, wc = wave&3;
  const u16* Ab = A_g + (size_t)b*sAb + (size_t)(bm*128)*lda;
  const u16* Bb = B_g + (size_t)b*sBb + (size_t)(bn*128)*ldb;
  f32x4 acc[4][2];
  #pragma unroll
  for (int i=0;i<4;i++)
    #pragma unroll
    for (int j=0;j<2;j++) acc[i][j] = (f32x4){0.f,0.f,0.f,0.f};

  for (int k0 = 0; k0 < K; k0 += 64){
    __syncthreads();
    stage_tile8(As, Ab + k0, lda, wave, lane);
    stage_tile8(Bs, Bb + k0, ldb, wave, lane);
    __syncthreads();
    #pragma unroll
    for (int kk=0;kk<2;kk++){
      const int ko = kk*32 + ((lane>>4)<<3);
      f16x8 a[4], bb[2];
      #pragma unroll
      for (int mi=0;mi<4;mi++) a[mi]  = frag_ld(As, wr*64 + mi*16 + (lane&15), ko);
      #pragma unroll
      for (int ni=0;ni<2;ni++) bb[ni] = frag_ld(Bs, wc*32 + ni*16 + (lane&15), ko);
      #pragma unroll
      for (int mi=0;mi<4;mi++)
        #pragma unroll
        for (int ni=0;ni<2;ni++)
          acc[mi][ni] = __builtin_amdgcn_mfma_f32_16x16x32_f16(a[mi], bb[ni], acc[mi][ni], 0,0,0);
    }
  }
  const int m0 = bm*128, n0 = bn*128;
  if (EPI == 0){
    float* Cb = C + (size_t)b*sCb;
    #pragma unroll
    for (int mi=0;mi<4;mi++)
      #pragma unroll
      for (int ni=0;ni<2;ni++){
        const int r = m0 + wr*64 + mi*16 + ((lane>>4)<<2);
        const int c = n0 + wc*32 + ni*16 + (lane&15);
        #pragma unroll
        for (int j=0;j<4;j++)
          Cb[(size_t)(r+j)*ldc + c] = acc[mi][ni][j];
      }
  } else {
    #pragma unroll
    for (int mi=0;mi<4;mi++)
      #pragma unroll
      for (int ni=0;ni<2;ni++){
        const int r = m0 + wr*64 + mi*16 + ((lane>>4)<<2);
        const int c = n0 + wc*32 + ni*16 + (lane&15);
        const float bv = bias[c];
        #pragma unroll
        for (int j=0;j<4;j++)
          Oh[(size_t)(r+j)*ldc + c] = f2h(acc[mi][ni][j] + bv);
      }
  }
}

// ---------- kernel: row softmax f32->fp16 in place (attn at row byte offset row*8192) ----------
__global__ __launch_bounds__(256) void softmax_k(float* __restrict__ sim){
  const int row = blockIdx.x;            // b*2048 + l
  float* p = sim + (size_t)row * LL;
  const int tid = threadIdx.x, wave = tid>>6, lane = tid&63;
  f32x4 x0 = reinterpret_cast<const f32x4*>(p)[tid];
  f32x4 x1 = reinterpret_cast<const f32x4*>(p)[tid + 256];
  float mx = fmaxf(fmaxf(fmaxf(x0[0],x0[1]), fmaxf(x0[2],x0[3])),
                   fmaxf(fmaxf(x1[0],x1[1]), fmaxf(x1[2],x1[3])));
  #pragma unroll
  for (int o = 32; o; o >>= 1) mx = fmaxf(mx, __shfl_xor(mx, o, 64));
  __shared__ float red[8];
  if (lane == 0) red[wave] = mx;
  __syncthreads();
  mx = fmaxf(fmaxf(red[0], red[1]), fmaxf(red[2], red[3]));
  float e0[4], e1[4], s = 0.f;
  #pragma unroll
  for (int j=0;j<4;j++){ e0[j] = __expf(x0[j]-mx); s += e0[j]; }
  #pragma unroll
  for (int j=0;j<4;j++){ e1[j] = __expf(x1[j]-mx); s += e1[j]; }
  #pragma unroll
  for (int o = 32; o; o >>= 1) s += __shfl_xor(s, o, 64);
  if (lane == 0) red[4+wave] = s;
  __syncthreads();
  s = (red[4]+red[5]) + (red[6]+red[7]);
  const float inv = 1.0f / s;
  u16* ob = reinterpret_cast<u16*>(p);   // fp16 attn at row byte base row*8192
  u16x4 w0, w1;
  #pragma unroll
  for (int j=0;j<4;j++){ w0[j] = f2h(e0[j]*inv); w1[j] = f2h(e1[j]*inv); }
  reinterpret_cast<u16x4*>(ob)[tid]       = w0;
  reinterpret_cast<u16x4*>(ob)[tid + 256] = w1;
}

// ---------- kernel: fp16 transpose per batch [2048][1024] -> [1024][2048] ----------
__global__ void transpose_k(const u16* __restrict__ in, u16* __restrict__ out){
  __shared__ u16 t[32][33];
  const int b = blockIdx.z;
  const int e0 = blockIdx.x*32, m0 = blockIdx.y*32;
  const u16* src = in  + (size_t)b*LL*DD;
  u16* dst       = out + (size_t)b*DD*LL;
  for (int j = threadIdx.y; j < 32; j += 8)
    t[j][threadIdx.x] = src[(size_t)(m0+j)*DD + e0 + threadIdx.x];
  __syncthreads();
  for (int j = threadIdx.y; j < 32; j += 8)
    dst[(size_t)(e0+j)*LL + m0 + threadIdx.x] = t[threadIdx.x][j];
}

// ---------- kernel: ZT = (t1 @ W2^T)^T fp16, 8 waves, swizzled ----------
__global__ __launch_bounds__(512,4) void gemm_zt_k(const u16* __restrict__ t1f,
                                                   const u16* __restrict__ w2f,
                                                   u16* __restrict__ ZT){
  __shared__ __align__(16) u16 As[128*64];
  __shared__ __align__(16) u16 Bs[128*64];
  const int bx = xcd_swz(blockIdx.x, gridDim.x);
  const int bm = bx >> 3, bn = bx & 7;
  const int tid = threadIdx.x, wave = tid>>6, lane = tid&63;
  const int wr = wave>>2, wc = wave&3;
  const u16* Ab = t1f + (size_t)(bm*128)*DD;
  const u16* Bb = w2f + (size_t)(bn*128)*DD;
  f32x4 acc[4][2];
  #pragma unroll
  for (int i=0;i<4;i++)
    #pragma unroll
    for (int j=0;j<2;j++) acc[i][j] = (f32x4){0.f,0.f,0.f,0.f};

  for (int k0 = 0; k0 < DD; k0 += 64){
    __syncthreads();
    stage_tile8(As, Ab + k0, DD, wave, lane);
    stage_tile8(Bs, Bb + k0, DD, wave, lane);
    __syncthreads();
    #pragma unroll
    for (int kk=0;kk<2;kk++){
      const int ko = kk*32 + ((lane>>4)<<3);
      f16x8 a[4], bb[2];
      #pragma unroll
      for (int mi=0;mi<4;mi++) a[mi]  = frag_ld(As, wr*64 + mi*16 + (lane&15), ko);
      #pragma unroll
      for (int ni=0;ni<2;ni++) bb[ni] = frag_ld(Bs, wc*32 + ni*16 + (lane&15), ko);
      #pragma unroll
      for (int mi=0;mi<4;mi++)
        #pragma unroll
        for (int ni=0;ni<2;ni++)
          acc[mi][ni] = __builtin_amdgcn_mfma_f32_16x16x32_f16(a[mi], bb[ni], acc[mi][ni], 0,0,0);
    }
  }
  #pragma unroll
  for (int mi=0;mi<4;mi++)
    #pragma unroll
    for (int ni=0;ni<2;ni++){
      const int l = bm*128 + wr*64 + mi*16 + ((lane>>4)<<2);  // global row (b*2048+m)
      const int b2i = l >> 11, m = l & 2047;
      const int d = bn*128 + wc*32 + ni*16 + (lane&15);
      u16x4 w;
      #pragma unroll
      for (int j=0;j<4;j++) w[j] = f2h(acc[mi][ni][j]);
      *reinterpret_cast<u16x4*>(ZT + ((size_t)b2i*DD + d)*LL + m) = w;
    }
}

// ---------- kernel: merged PV GEMM — out1 = attn@f2, out2 = attn@Z + b2 ----------
// A = attn fp16 [b][2048] rows at stride 4096 elems. B per bn: bn<8 -> f2T, else ZT
// (both [b][1024][2048], ld=LL). grid (256, BB): bm=bx>>4, bn=bx&15. K=2048.
__global__ __launch_bounds__(512,4) void gemm_pv_k(const u16* __restrict__ attn,
                                                   const u16* __restrict__ f2T,
                                                   const u16* __restrict__ ZT,
                                                   float* __restrict__ out1,
                                                   float* __restrict__ out2,
                                                   const float* __restrict__ b2){
  __shared__ __align__(16) u16 As[128*64];
  __shared__ __align__(16) u16 Bs[128*64];
  const int b = blockIdx.y;
  const int bx = xcd_swz(blockIdx.x, gridDim.x);
  const int bm = bx >> 4, bn = bx & 15;
  const int tid = threadIdx.x, wave = tid>>6, lane = tid&63;
  const int wr = wave>>2, wc = wave&3;
  const u16* Ab = attn + (size_t)b*LL*4096 + (size_t)(bm*128)*4096;
  const u16* Bbase = (bn < 8) ? f2T : ZT;
  const int d0 = (bn & 7) * 128;
  const u16* Bb = Bbase + (size_t)b*DD*LL + (size_t)d0*LL;
  f32x4 acc[4][2];
  #pragma unroll
  for (int i=0;i<4;i++)
    #pragma unroll
    for (int j=0;j<2;j++) acc[i][j] = (f32x4){0.f,0.f,0.f,0.f};

  for (int k0 = 0; k0 < LL; k0 += 64){
    __syncthreads();
    stage_tile8(As, Ab + k0, 4096, wave, lane);
    stage_tile8(Bs, Bb + k0, LL, wave, lane);
    __syncthreads();
    #pragma unroll
    for (int kk=0;kk<2;kk++){
      const int ko = kk*32 + ((lane>>4)<<3);
      f16x8 a[4], bb[2];
      #pragma unroll
      for (int mi=0;mi<4;mi++) a[mi]  = frag_ld(As, wr*64 + mi*16 + (lane&15), ko);
      #pragma unroll
      for (int ni=0;ni<2;ni++) bb[ni] = frag_ld(Bs, wc*32 + ni*16 + (lane&15), ko);
      #pragma unroll
      for (int mi=0;mi<4;mi++)
        #pragma unroll
        for (int ni=0;ni<2;ni++)
          acc[mi][ni] = __builtin_amdgcn_mfma_f32_16x16x32_f16(a[mi], bb[ni], acc[mi][ni], 0,0,0);
    }
  }
  float* O = ((bn < 8) ? out1 : out2) + (size_t)b*LL*DD;
  const bool has_bias = (bn >= 8);
  #pragma unroll
  for (int mi=0;mi<4;mi++)
    #pragma unroll
    for (int ni=0;ni<2;ni++){
      const int r = bm*128 + wr*64 + mi*16 + ((lane>>4)<<2);
      const int c = d0 + wc*32 + ni*16 + (lane&15);
      const float bv = has_bias ? b2[c] : 0.f;
      #pragma unroll
      for (int j=0;j<4;j++)
        O[(size_t)(r+j)*DD + c] = acc[mi][ni][j] + bv;
    }
}

// ---------- host launch ----------
extern "C" void kernel_launch(void* const* d_in, const int* in_sizes, int n_in,
                              void* d_out, int out_size, void* d_ws, size_t ws_size,
                              hipStream_t stream) {
  const float* f1 = (const float*)d_in[0];
  const float* f2 = (const float*)d_in[1];
  const float* W1 = (const float*)d_in[2];
  const float* b1 = (const float*)d_in[3];
  const float* W2 = (const float*)d_in[4];
  const float* b2 = (const float*)d_in[5];
  float* out1 = (float*)d_out;
  float* out2 = out1 + (size_t)BB*LL*DD;

  // workspace layout (bytes); peak 132 MB
  char* ws = (char*)d_ws;
  u16* t1f = (u16*)(ws + 0);              // 16 MiB  fp16 t1 [b*2048][1024]
  u16* ZT  = (u16*)(ws + 16777216);       // 16 MiB  fp16 Z^T [b][1024][2048]
  u16* f2f = (u16*)(ws + 33554432);       // 16 MiB  fp16 f2 [b][2048][1024]
  u16* f2T = (u16*)(ws + 50331648);       // 16 MiB  fp16 f2^T [b][1024][2048]
  u16* w1f = (u16*)(ws + 67108864);       // 2 MiB
  u16* w2f = (u16*)(ws + 69206016);       // 2 MiB
  float* sim = (float*)(ws + 71303168);   // 64 MiB f32; attn fp16 written in place
  u16* f1f = (u16*)(ws + 71303168);       // 16 MiB, aliases sim (dead before sim GEMM)

  // 1. casts f32 -> fp16
  cast_k<<<4096, 256, 0, stream>>>(f2, f2f, (BB*LL*DD)/4);
  cast_k<<<4096, 256, 0, stream>>>(f1, f1f, (BB*LL*DD)/4);
  cast_k<<<1024, 256, 0, stream>>>(W1, w1f, (DD*DD)/4);
  cast_k<<<1024, 256, 0, stream>>>(W2, w2f, (DD*DD)/4);
  // 2. t1 = f1 @ W1^T + b1 (fp16). tiles 64x8.
  gemm_h_k<1><<<dim3(512, 1), 512, 0, stream>>>(f1f, 0, DD,
                                                w1f, 0, DD,
                                                nullptr, 0, DD,
                                                b1, t1f, DD, 3);
  // 3. sim[b] = t1[b] @ f2[b]^T (fp16 -> f32). tiles 16x16 per batch.
  gemm_h_k<0><<<dim3(256, BB), 512, 0, stream>>>(t1f, (long long)LL*DD, DD,
                                                 f2f, (long long)LL*DD, DD,
                                                 sim, (long long)LL*LL, LL,
                                                 nullptr, nullptr, DD, 4);
  // 4. softmax rows, write attn fp16 in place
  softmax_k<<<BB*LL, 256, 0, stream>>>(sim);
  // 5. f2T = transpose(f2f)
  transpose_k<<<dim3(32, 64, BB), dim3(32, 8), 0, stream>>>(f2f, f2T);
  // 6. ZT = (t1 @ W2^T)^T fp16
  gemm_zt_k<<<dim3(512, 1), 512, 0, stream>>>(t1f, w2f, ZT);
  // 7. merged PV: out1 = attn@f2, out2 = attn@Z + b2
  gemm_pv_k<<<dim3(256, BB), 512, 0, stream>>>((const u16*)sim, f2T, ZT,
                                               out1, out2, b2);
}

// Round 5
// 213.793 us; speedup vs baseline: 1.7897x; 1.0346x over previous
//
#include <hip/hip_runtime.h>
#include <stdint.h>

// Problem constants
#define BB 4
#define LL 2048
#define DD 1024

typedef __attribute__((ext_vector_type(4))) float f32x4;
typedef __attribute__((ext_vector_type(8))) _Float16 f16x8;
typedef __attribute__((ext_vector_type(4))) unsigned short u16x4;
typedef unsigned short u16;

// ---------- fp16 helper ----------
__device__ __forceinline__ u16 f2h(float x){
  return __builtin_bit_cast(u16, (_Float16)x);
}

// ---------- async global->LDS staging (16B/lane) ----------
__device__ __forceinline__ void gload16(const u16* g, u16* l){
  __builtin_amdgcn_global_load_lds((const __attribute__((address_space(1))) unsigned*)g,
                                   (__attribute__((address_space(3))) unsigned*)l,
                                   16, 0, 0);
}

// XCD-aware chunked block swizzle (requires nwg % 8 == 0; all our grids comply)
__device__ __forceinline__ int xcd_swz(int bx, int nwg){
  return (bx & 7) * (nwg >> 3) + (bx >> 3);
}

// stage a [128][64] fp16 tile, 8 waves, XOR-swizzled (128-tile kernels)
__device__ __forceinline__ void stage_tile8(u16* lds, const u16* src, int ld, int wave, int lane){
  const int r0 = lane >> 3;
  const int cs = (((lane & 7) ^ r0) << 3);
  #pragma unroll
  for (int j = 0; j < 2; ++j){
    const int rb = wave*16 + j*8;
    gload16(src + (size_t)(rb + r0)*ld + cs, lds + rb*64);
  }
}

// swizzled fragment read: logical (row, ko) lives at phys col ko ^ ((row&7)<<3)
__device__ __forceinline__ f16x8 frag_ld(const u16* t, int row, int ko){
  return __builtin_bit_cast(f16x8,
    *reinterpret_cast<const f32x4*>(t + row*64 + (ko ^ ((row & 7) << 3))));
}

// ---------- kernel: f32 -> fp16 cast ----------
__global__ void cast_k(const float* __restrict__ src, u16* __restrict__ dst, int n4){
  const int stride = gridDim.x * blockDim.x;
  for (int i = blockIdx.x*blockDim.x + threadIdx.x; i < n4; i += stride){
    f32x4 v = reinterpret_cast<const f32x4*>(src)[i];
    u16x4 h;
    #pragma unroll
    for (int j = 0; j < 4; ++j) h[j] = f2h(v[j]);
    reinterpret_cast<u16x4*>(dst)[i] = h;
  }
}

// ================= 8-phase 256x256 fp16 GEMM (T2+T3+T4+T5) =================
// BM=BN=256, BK=64, 8 waves (512 thr). 4 half-slots per operand (128 KiB LDS).
// Phase p of tile t computes C-quadrant (qm=p>>1, qn=p&1); wave w covers
// rows qm*128+(w&1)*64, cols qn*128+(w>>1)*32. Stage schedule per tile t:
//   p0: A-h1(t+1)   p1: B-h1(t+1)   p2: A-h0(t+2)   p3: B-h0(t+2), vmcnt(4)
// Each slot is re-staged only after its last reader phase (barrier-enforced),
// and drained by the vmcnt one full tile before first use. NO __syncthreads.
// EPI=0: C0 = A@B0^T f32. EPI=1 (PV dual): bn<4 -> C0=A@B0^T, else C1=A@B1^T+bias.
template<int EPI>
__global__ __launch_bounds__(512,2) void gemm8p_k(
    const u16* __restrict__ A_g, long long sAb, int lda,
    const u16* __restrict__ B0_g, const u16* __restrict__ B1_g, long long sBb, int ldb,
    float* __restrict__ C0, float* __restrict__ C1, long long sCb, int ldc,
    const float* __restrict__ bias, int NT){
  __shared__ __align__(16) u16 As[4][128*64];
  __shared__ __align__(16) u16 Bs[4][128*64];
  const int b = blockIdx.y;
  const int bx = xcd_swz(blockIdx.x, gridDim.x);
  const int bm = bx >> 3, bn = bx & 7;
  const int tid = threadIdx.x, wave = tid>>6, lane = tid&63;
  const int wm = wave & 1, wn = wave >> 1;          // wave -> 64x32 sub-quadrant
  const int r0 = lane >> 3, cs = (((lane&7) ^ r0) << 3);
  const int rb0 = wave*16;
  const u16* Ab = A_g + (size_t)b*sAb + (size_t)(bm*256)*lda;
  const u16* Bb = (EPI == 0)
      ? (B0_g + (size_t)b*sBb + (size_t)(bn*256)*ldb)
      : (((bn < 4) ? B0_g : B1_g) + (size_t)b*sBb + (size_t)((bn&3)*256)*ldb);

  f32x4 acc[2][2][4][2];
  #pragma unroll
  for (int i=0;i<2;i++)
    #pragma unroll
    for (int j=0;j<2;j++)
      #pragma unroll
      for (int m=0;m<4;m++)
        #pragma unroll
        for (int n=0;n<2;n++) acc[i][j][m][n] = (f32x4){0.f,0.f,0.f,0.f};

  auto stA = [&](int tt, int h){
    const u16* s = Ab + (size_t)(h*128 + rb0 + r0)*lda + (size_t)tt*64 + cs;
    u16* d = &As[((tt&1)<<1)+h][rb0*64];
    gload16(s, d);
    gload16(s + (size_t)8*lda, d + 8*64);
  };
  auto stB = [&](int tt, int h){
    const u16* s = Bb + (size_t)(h*128 + rb0 + r0)*ldb + (size_t)tt*64 + cs;
    u16* d = &Bs[((tt&1)<<1)+h][rb0*64];
    gload16(s, d);
    gload16(s + (size_t)8*ldb, d + 8*64);
  };

  // prologue: tile0 (4 halves), then A-h0/B-h0 of tile1; drain tile0 only.
  stA(0,0); stB(0,0); stA(0,1); stB(0,1);
  stA(1,0); stB(1,0);
  asm volatile("s_waitcnt vmcnt(4)" ::: "memory");
  __builtin_amdgcn_s_barrier();

  for (int t = 0; t < NT; ++t){
    #pragma unroll
    for (int p = 0; p < 4; ++p){
      const u16* Ah = As[((t&1)<<1) + (p>>1)];
      const u16* Bh = Bs[((t&1)<<1) + (p&1)];
      f16x8 af[4][2], bf[2][2];
      #pragma unroll
      for (int mi=0;mi<4;mi++)
        #pragma unroll
        for (int ks=0;ks<2;ks++)
          af[mi][ks] = frag_ld(Ah, wm*64 + mi*16 + (lane&15), ks*32 + ((lane>>4)<<3));
      #pragma unroll
      for (int ni=0;ni<2;ni++)
        #pragma unroll
        for (int ks=0;ks<2;ks++)
          bf[ni][ks] = frag_ld(Bh, wn*32 + ni*16 + (lane&15), ks*32 + ((lane>>4)<<3));
      // stage one half-tile (slot freed by last phase's barrier)
      if (p == 0){ if (t+1 < NT) stA(t+1, 1); }
      else if (p == 1){ if (t+1 < NT) stB(t+1, 1); }
      else if (p == 2){ if (t+2 < NT) stA(t+2, 0); }
      else {
        if (t+2 < NT){ stB(t+2, 0); asm volatile("s_waitcnt vmcnt(4)" ::: "memory"); }
        else         {              asm volatile("s_waitcnt vmcnt(0)" ::: "memory"); }
      }
      __builtin_amdgcn_s_barrier();
      asm volatile("s_waitcnt lgkmcnt(0)" ::: "memory");
      __builtin_amdgcn_sched_barrier(0);
      __builtin_amdgcn_s_setprio(1);
      #pragma unroll
      for (int mi=0;mi<4;mi++)
        #pragma unroll
        for (int ni=0;ni<2;ni++)
          #pragma unroll
          for (int ks=0;ks<2;ks++)
            acc[p>>1][p&1][mi][ni] = __builtin_amdgcn_mfma_f32_16x16x32_f16(
                af[mi][ks], bf[ni][ks], acc[p>>1][p&1][mi][ni], 0,0,0);
      __builtin_amdgcn_s_setprio(0);
      __builtin_amdgcn_sched_barrier(0);
      __builtin_amdgcn_s_barrier();
    }
  }

  // epilogue (registers -> global; no LDS use, no barrier needed)
  #pragma unroll
  for (int qm=0;qm<2;qm++)
    #pragma unroll
    for (int qn=0;qn<2;qn++)
      #pragma unroll
      for (int mi=0;mi<4;mi++)
        #pragma unroll
        for (int ni=0;ni<2;ni++){
          const int r = bm*256 + qm*128 + wm*64 + mi*16 + ((lane>>4)<<2);
          if (EPI == 0){
            const int c = bn*256 + qn*128 + wn*32 + ni*16 + (lane&15);
            float* Cb = C0 + (size_t)b*sCb;
            #pragma unroll
            for (int j=0;j<4;j++)
              Cb[(size_t)(r+j)*ldc + c] = acc[qm][qn][mi][ni][j];
          } else {
            const int c = (bn&3)*256 + qn*128 + wn*32 + ni*16 + (lane&15);
            float* O = ((bn < 4) ? C0 : C1) + (size_t)b*sCb;
            const float bv = (bn >= 4) ? bias[c] : 0.f;
            #pragma unroll
            for (int j=0;j<4;j++)
              O[(size_t)(r+j)*ldc + c] = acc[qm][qn][mi][ni][j] + bv;
          }
        }
}

// ---------- fp16 GEMM 128x128 (kept for t1), 8 waves ----------
template<int EPI>
__global__ __launch_bounds__(512,4) void gemm_h_k(
    const u16* __restrict__ A_g, long long sAb, int lda,
    const u16* __restrict__ B_g, long long sBb, int ldb,
    float* __restrict__ C, long long sCb, int ldc,
    const float* __restrict__ bias, u16* __restrict__ Oh,
    int K, int tn_sh){
  __shared__ __align__(16) u16 As[128*64];
  __shared__ __align__(16) u16 Bs[128*64];
  const int b = blockIdx.y;
  const int bx = xcd_swz(blockIdx.x, gridDim.x);
  const int bm = bx >> tn_sh, bn = bx & ((1 << tn_sh) - 1);
  const int tid = threadIdx.x, wave = tid>>6, lane = tid&63;
  const int wr = wave>>2, wc = wave&3;
  const u16* Ab = A_g + (size_t)b*sAb + (size_t)(bm*128)*lda;
  const u16* Bb = B_g + (size_t)b*sBb + (size_t)(bn*128)*ldb;
  f32x4 acc[4][2];
  #pragma unroll
  for (int i=0;i<4;i++)
    #pragma unroll
    for (int j=0;j<2;j++) acc[i][j] = (f32x4){0.f,0.f,0.f,0.f};

  for (int k0 = 0; k0 < K; k0 += 64){
    __syncthreads();
    stage_tile8(As, Ab + k0, lda, wave, lane);
    stage_tile8(Bs, Bb + k0, ldb, wave, lane);
    __syncthreads();
    #pragma unroll
    for (int kk=0;kk<2;kk++){
      const int ko = kk*32 + ((lane>>4)<<3);
      f16x8 a[4], bb[2];
      #pragma unroll
      for (int mi=0;mi<4;mi++) a[mi]  = frag_ld(As, wr*64 + mi*16 + (lane&15), ko);
      #pragma unroll
      for (int ni=0;ni<2;ni++) bb[ni] = frag_ld(Bs, wc*32 + ni*16 + (lane&15), ko);
      #pragma unroll
      for (int mi=0;mi<4;mi++)
        #pragma unroll
        for (int ni=0;ni<2;ni++)
          acc[mi][ni] = __builtin_amdgcn_mfma_f32_16x16x32_f16(a[mi], bb[ni], acc[mi][ni], 0,0,0);
    }
  }
  const int m0 = bm*128, n0 = bn*128;
  if (EPI == 0){
    float* Cb = C + (size_t)b*sCb;
    #pragma unroll
    for (int mi=0;mi<4;mi++)
      #pragma unroll
      for (int ni=0;ni<2;ni++){
        const int r = m0 + wr*64 + mi*16 + ((lane>>4)<<2);
        const int c = n0 + wc*32 + ni*16 + (lane&15);
        #pragma unroll
        for (int j=0;j<4;j++)
          Cb[(size_t)(r+j)*ldc + c] = acc[mi][ni][j];
      }
  } else {
    #pragma unroll
    for (int mi=0;mi<4;mi++)
      #pragma unroll
      for (int ni=0;ni<2;ni++){
        const int r = m0 + wr*64 + mi*16 + ((lane>>4)<<2);
        const int c = n0 + wc*32 + ni*16 + (lane&15);
        const float bv = bias[c];
        #pragma unroll
        for (int j=0;j<4;j++)
          Oh[(size_t)(r+j)*ldc + c] = f2h(acc[mi][ni][j] + bv);
      }
  }
}

// ---------- kernel: row softmax f32->fp16 in place ----------
__global__ __launch_bounds__(256) void softmax_k(float* __restrict__ sim){
  const int row = blockIdx.x;
  float* p = sim + (size_t)row * LL;
  const int tid = threadIdx.x, wave = tid>>6, lane = tid&63;
  f32x4 x0 = reinterpret_cast<const f32x4*>(p)[tid];
  f32x4 x1 = reinterpret_cast<const f32x4*>(p)[tid + 256];
  float mx = fmaxf(fmaxf(fmaxf(x0[0],x0[1]), fmaxf(x0[2],x0[3])),
                   fmaxf(fmaxf(x1[0],x1[1]), fmaxf(x1[2],x1[3])));
  #pragma unroll
  for (int o = 32; o; o >>= 1) mx = fmaxf(mx, __shfl_xor(mx, o, 64));
  __shared__ float red[8];
  if (lane == 0) red[wave] = mx;
  __syncthreads();
  mx = fmaxf(fmaxf(red[0], red[1]), fmaxf(red[2], red[3]));
  float e0[4], e1[4], s = 0.f;
  #pragma unroll
  for (int j=0;j<4;j++){ e0[j] = __expf(x0[j]-mx); s += e0[j]; }
  #pragma unroll
  for (int j=0;j<4;j++){ e1[j] = __expf(x1[j]-mx); s += e1[j]; }
  #pragma unroll
  for (int o = 32; o; o >>= 1) s += __shfl_xor(s, o, 64);
  if (lane == 0) red[4+wave] = s;
  __syncthreads();
  s = (red[4]+red[5]) + (red[6]+red[7]);
  const float inv = 1.0f / s;
  u16* ob = reinterpret_cast<u16*>(p);
  u16x4 w0, w1;
  #pragma unroll
  for (int j=0;j<4;j++){ w0[j] = f2h(e0[j]*inv); w1[j] = f2h(e1[j]*inv); }
  reinterpret_cast<u16x4*>(ob)[tid]       = w0;
  reinterpret_cast<u16x4*>(ob)[tid + 256] = w1;
}

// ---------- kernel: fp16 transpose per batch [2048][1024] -> [1024][2048] ----------
__global__ void transpose_k(const u16* __restrict__ in, u16* __restrict__ out){
  __shared__ u16 t[32][33];
  const int b = blockIdx.z;
  const int e0 = blockIdx.x*32, m0 = blockIdx.y*32;
  const u16* src = in  + (size_t)b*LL*DD;
  u16* dst       = out + (size_t)b*DD*LL;
  for (int j = threadIdx.y; j < 32; j += 8)
    t[j][threadIdx.x] = src[(size_t)(m0+j)*DD + e0 + threadIdx.x];
  __syncthreads();
  for (int j = threadIdx.y; j < 32; j += 8)
    dst[(size_t)(e0+j)*LL + m0 + threadIdx.x] = t[threadIdx.x][j];
}

// ---------- kernel: ZT = (t1 @ W2^T)^T fp16, 128-tile ----------
__global__ __launch_bounds__(512,4) void gemm_zt_k(const u16* __restrict__ t1f,
                                                   const u16* __restrict__ w2f,
                                                   u16* __restrict__ ZT){
  __shared__ __align__(16) u16 As[128*64];
  __shared__ __align__(16) u16 Bs[128*64];
  const int bx = xcd_swz(blockIdx.x, gridDim.x);
  const int bm = bx >> 3, bn = bx & 7;
  const int tid = threadIdx.x, wave = tid>>6, lane = tid&63;
  const int wr = wave>>2, wc = wave&3;
  const u16* Ab = t1f + (size_t)(bm*128)*DD;
  const u16* Bb = w2f + (size_t)(bn*128)*DD;
  f32x4 acc[4][2];
  #pragma unroll
  for (int i=0;i<4;i++)
    #pragma unroll
    for (int j=0;j<2;j++) acc[i][j] = (f32x4){0.f,0.f,0.f,0.f};

  for (int k0 = 0; k0 < DD; k0 += 64){
    __syncthreads();
    stage_tile8(As, Ab + k0, DD, wave, lane);
    stage_tile8(Bs, Bb + k0, DD, wave, lane);
    __syncthreads();
    #pragma unroll
    for (int kk=0;kk<2;kk++){
      const int ko = kk*32 + ((lane>>4)<<3);
      f16x8 a[4], bb[2];
      #pragma unroll
      for (int mi=0;mi<4;mi++) a[mi]  = frag_ld(As, wr*64 + mi*16 + (lane&15), ko);
      #pragma unroll
      for (int ni=0;ni<2;ni++) bb[ni] = frag_ld(Bs, wc*32 + ni*16 + (lane&15), ko);
      #pragma unroll
      for (int mi=0;mi<4;mi++)
        #pragma unroll
        for (int ni=0;ni<2;ni++)
          acc[mi][ni] = __builtin_amdgcn_mfma_f32_16x16x32_f16(a[mi], bb[ni], acc[mi][ni], 0,0,0);
    }
  }
  #pragma unroll
  for (int mi=0;mi<4;mi++)
    #pragma unroll
    for (int ni=0;ni<2;ni++){
      const int l = bm*128 + wr*64 + mi*16 + ((lane>>4)<<2);
      const int b2i = l >> 11, m = l & 2047;
      const int d = bn*128 + wc*32 + ni*16 + (lane&15);
      u16x4 w;
      #pragma unroll
      for (int j=0;j<4;j++) w[j] = f2h(acc[mi][ni][j]);
      *reinterpret_cast<u16x4*>(ZT + ((size_t)b2i*DD + d)*LL + m) = w;
    }
}

// ---------- host launch ----------
extern "C" void kernel_launch(void* const* d_in, const int* in_sizes, int n_in,
                              void* d_out, int out_size, void* d_ws, size_t ws_size,
                              hipStream_t stream) {
  const float* f1 = (const float*)d_in[0];
  const float* f2 = (const float*)d_in[1];
  const float* W1 = (const float*)d_in[2];
  const float* b1 = (const float*)d_in[3];
  const float* W2 = (const float*)d_in[4];
  const float* b2 = (const float*)d_in[5];
  float* out1 = (float*)d_out;
  float* out2 = out1 + (size_t)BB*LL*DD;

  // workspace layout (bytes); peak 132 MB
  char* ws = (char*)d_ws;
  u16* t1f = (u16*)(ws + 0);              // 16 MiB  fp16 t1 [b*2048][1024]
  u16* ZT  = (u16*)(ws + 16777216);       // 16 MiB  fp16 Z^T [b][1024][2048]
  u16* f2f = (u16*)(ws + 33554432);       // 16 MiB  fp16 f2 [b][2048][1024]
  u16* f2T = (u16*)(ws + 50331648);       // 16 MiB  fp16 f2^T [b][1024][2048]
  u16* w1f = (u16*)(ws + 67108864);       // 2 MiB
  u16* w2f = (u16*)(ws + 69206016);       // 2 MiB
  float* sim = (float*)(ws + 71303168);   // 64 MiB f32; attn fp16 written in place
  u16* f1f = (u16*)(ws + 71303168);       // 16 MiB, aliases sim (dead before sim GEMM)

  // 1. casts f32 -> fp16
  cast_k<<<4096, 256, 0, stream>>>(f2, f2f, (BB*LL*DD)/4);
  cast_k<<<4096, 256, 0, stream>>>(f1, f1f, (BB*LL*DD)/4);
  cast_k<<<1024, 256, 0, stream>>>(W1, w1f, (DD*DD)/4);
  cast_k<<<1024, 256, 0, stream>>>(W2, w2f, (DD*DD)/4);
  // 2. t1 = f1 @ W1^T + b1 (fp16), 128-tile. tiles 64x8.
  gemm_h_k<1><<<dim3(512, 1), 512, 0, stream>>>(f1f, 0, DD,
                                                w1f, 0, DD,
                                                nullptr, 0, DD,
                                                b1, t1f, DD, 3);
  // 3. sim[b] = t1[b] @ f2[b]^T — 8-phase 256x256. tiles 8x8 per batch, NT=16.
  gemm8p_k<0><<<dim3(64, BB), 512, 0, stream>>>(t1f, (long long)LL*DD, DD,
                                                f2f, nullptr, (long long)LL*DD, DD,
                                                sim, nullptr, (long long)LL*LL, LL,
                                                nullptr, 16);
  // 4. softmax rows, write attn fp16 in place (row stride 4096 elems)
  softmax_k<<<BB*LL, 256, 0, stream>>>(sim);
  // 5. f2T = transpose(f2f)
  transpose_k<<<dim3(32, 64, BB), dim3(32, 8), 0, stream>>>(f2f, f2T);
  // 6. ZT = (t1 @ W2^T)^T fp16
  gemm_zt_k<<<dim3(512, 1), 512, 0, stream>>>(t1f, w2f, ZT);
  // 7. merged PV — 8-phase 256x256: bn<4 -> out1 = attn@f2, bn>=4 -> out2 = attn@Z + b2.
  //    NT=32 (K=2048).
  gemm8p_k<1><<<dim3(64, BB), 512, 0, stream>>>((const u16*)sim, (long long)LL*4096, 4096,
                                                f2T, ZT, (long long)DD*LL, LL,
                                                out1, out2, (long long)LL*DD, DD,
                                                b2, 32);
}

// Round 6
// 209.737 us; speedup vs baseline: 1.8243x; 1.0193x over previous
//
#include <hip/hip_runtime.h>
#include <stdint.h>

// Problem constants
#define BB 4
#define LL 2048
#define DD 1024

typedef __attribute__((ext_vector_type(4))) float f32x4;
typedef __attribute__((ext_vector_type(8))) _Float16 f16x8;
typedef __attribute__((ext_vector_type(4))) unsigned short u16x4;
typedef __attribute__((ext_vector_type(8))) unsigned short u16x8;
typedef unsigned short u16;

// ---------- fp16 helper ----------
__device__ __forceinline__ u16 f2h(float x){
  return __builtin_bit_cast(u16, (_Float16)x);
}

// ---------- async global->LDS staging (16B/lane) ----------
__device__ __forceinline__ void gload16(const u16* g, u16* l){
  __builtin_amdgcn_global_load_lds((const __attribute__((address_space(1))) unsigned*)g,
                                   (__attribute__((address_space(3))) unsigned*)l,
                                   16, 0, 0);
}

// XCD-aware chunked block swizzle (requires nwg % 8 == 0; all our grids comply)
__device__ __forceinline__ int xcd_swz(int bx, int nwg){
  return (bx & 7) * (nwg >> 3) + (bx >> 3);
}

// stage a [128][64] fp16 tile, 8 waves, XOR-swizzled (128-tile kernels)
__device__ __forceinline__ void stage_tile8(u16* lds, const u16* src, int ld, int wave, int lane){
  const int r0 = lane >> 3;
  const int cs = (((lane & 7) ^ r0) << 3);
  #pragma unroll
  for (int j = 0; j < 2; ++j){
    const int rb = wave*16 + j*8;
    gload16(src + (size_t)(rb + r0)*ld + cs, lds + rb*64);
  }
}

// swizzled fragment read: logical (row, ko) lives at phys col ko ^ ((row&7)<<3)
__device__ __forceinline__ f16x8 frag_ld(const u16* t, int row, int ko){
  return __builtin_bit_cast(f16x8,
    *reinterpret_cast<const f32x4*>(t + row*64 + (ko ^ ((row & 7) << 3))));
}

// ---------- kernel: fused casts f1 -> f1f, W1 -> w1f, W2 -> w2f ----------
__global__ void cast3_k(const float* __restrict__ f1, u16* __restrict__ f1f,
                        const float* __restrict__ W1, u16* __restrict__ w1f,
                        const float* __restrict__ W2, u16* __restrict__ w2f){
  const int n1 = (BB*LL*DD)/4, nw = (DD*DD)/4;
  const int stride = gridDim.x * blockDim.x;
  for (int i = blockIdx.x*blockDim.x + threadIdx.x; i < n1 + 2*nw; i += stride){
    const float* s; u16* d; int k;
    if (i < n1){ s = f1; d = f1f; k = i; }
    else if (i < n1 + nw){ s = W1; d = w1f; k = i - n1; }
    else { s = W2; d = w2f; k = i - n1 - nw; }
    f32x4 v = reinterpret_cast<const f32x4*>(s)[k];
    u16x4 h;
    #pragma unroll
    for (int j = 0; j < 4; ++j) h[j] = f2h(v[j]);
    reinterpret_cast<u16x4*>(d)[k] = h;
  }
}

// ---------- kernel: f2 f32 -> fp16 cast + transpose in one pass ----------
// grid (32 d-tiles, 64 l-tiles, BB), block (32,8). Writes f2f[b][l][d] and f2T[b][d][l].
__global__ void castT_k(const float* __restrict__ f2, u16* __restrict__ f2f,
                        u16* __restrict__ f2T){
  __shared__ u16 t[32][33];
  const int b = blockIdx.z;
  const int d0 = blockIdx.x*32, l0 = blockIdx.y*32;
  const float* src = f2 + (size_t)b*LL*DD;
  u16* d1 = f2f + (size_t)b*LL*DD;
  u16* d2 = f2T + (size_t)b*DD*LL;
  const int x = threadIdx.x;
  for (int j = threadIdx.y; j < 32; j += 8){
    u16 h = f2h(src[(size_t)(l0+j)*DD + d0 + x]);
    d1[(size_t)(l0+j)*DD + d0 + x] = h;
    t[j][x] = h;   // t[li][di]
  }
  __syncthreads();
  for (int j = threadIdx.y; j < 32; j += 8)
    d2[(size_t)(d0+j)*LL + l0 + x] = t[x][j];
}

// ================= 8-phase 256x256 fp16 GEMM (sim only) =================
// BM=BN=256, BK=64, 8 waves. 4 half-slots/operand (128 KiB LDS). See r5 notes.
__global__ __launch_bounds__(512,2) void gemm8p_k(
    const u16* __restrict__ A_g, long long sAb, int lda,
    const u16* __restrict__ B_g, long long sBb, int ldb,
    float* __restrict__ C, long long sCb, int ldc, int NT){
  __shared__ __align__(16) u16 As[4][128*64];
  __shared__ __align__(16) u16 Bs[4][128*64];
  const int b = blockIdx.y;
  const int bx = xcd_swz(blockIdx.x, gridDim.x);
  const int bm = bx >> 3, bn = bx & 7;
  const int tid = threadIdx.x, wave = tid>>6, lane = tid&63;
  const int wm = wave & 1, wn = wave >> 1;
  const int r0 = lane >> 3, cs = (((lane&7) ^ r0) << 3);
  const int rb0 = wave*16;
  const u16* Ab = A_g + (size_t)b*sAb + (size_t)(bm*256)*lda;
  const u16* Bb = B_g + (size_t)b*sBb + (size_t)(bn*256)*ldb;

  f32x4 acc[2][2][4][2];
  #pragma unroll
  for (int i=0;i<2;i++)
    #pragma unroll
    for (int j=0;j<2;j++)
      #pragma unroll
      for (int m=0;m<4;m++)
        #pragma unroll
        for (int n=0;n<2;n++) acc[i][j][m][n] = (f32x4){0.f,0.f,0.f,0.f};

  auto stA = [&](int tt, int h){
    const u16* s = Ab + (size_t)(h*128 + rb0 + r0)*lda + (size_t)tt*64 + cs;
    u16* d = &As[((tt&1)<<1)+h][rb0*64];
    gload16(s, d);
    gload16(s + (size_t)8*lda, d + 8*64);
  };
  auto stB = [&](int tt, int h){
    const u16* s = Bb + (size_t)(h*128 + rb0 + r0)*ldb + (size_t)tt*64 + cs;
    u16* d = &Bs[((tt&1)<<1)+h][rb0*64];
    gload16(s, d);
    gload16(s + (size_t)8*ldb, d + 8*64);
  };

  stA(0,0); stB(0,0); stA(0,1); stB(0,1);
  stA(1,0); stB(1,0);
  asm volatile("s_waitcnt vmcnt(4)" ::: "memory");
  __builtin_amdgcn_s_barrier();

  for (int t = 0; t < NT; ++t){
    #pragma unroll
    for (int p = 0; p < 4; ++p){
      const u16* Ah = As[((t&1)<<1) + (p>>1)];
      const u16* Bh = Bs[((t&1)<<1) + (p&1)];
      f16x8 af[4][2], bf[2][2];
      #pragma unroll
      for (int mi=0;mi<4;mi++)
        #pragma unroll
        for (int ks=0;ks<2;ks++)
          af[mi][ks] = frag_ld(Ah, wm*64 + mi*16 + (lane&15), ks*32 + ((lane>>4)<<3));
      #pragma unroll
      for (int ni=0;ni<2;ni++)
        #pragma unroll
        for (int ks=0;ks<2;ks++)
          bf[ni][ks] = frag_ld(Bh, wn*32 + ni*16 + (lane&15), ks*32 + ((lane>>4)<<3));
      if (p == 0){ if (t+1 < NT) stA(t+1, 1); }
      else if (p == 1){ if (t+1 < NT) stB(t+1, 1); }
      else if (p == 2){ if (t+2 < NT) stA(t+2, 0); }
      else {
        if (t+2 < NT){ stB(t+2, 0); asm volatile("s_waitcnt vmcnt(4)" ::: "memory"); }
        else         {              asm volatile("s_waitcnt vmcnt(0)" ::: "memory"); }
      }
      __builtin_amdgcn_s_barrier();
      asm volatile("s_waitcnt lgkmcnt(0)" ::: "memory");
      __builtin_amdgcn_sched_barrier(0);
      __builtin_amdgcn_s_setprio(1);
      #pragma unroll
      for (int mi=0;mi<4;mi++)
        #pragma unroll
        for (int ni=0;ni<2;ni++)
          #pragma unroll
          for (int ks=0;ks<2;ks++)
            acc[p>>1][p&1][mi][ni] = __builtin_amdgcn_mfma_f32_16x16x32_f16(
                af[mi][ks], bf[ni][ks], acc[p>>1][p&1][mi][ni], 0,0,0);
      __builtin_amdgcn_s_setprio(0);
      __builtin_amdgcn_sched_barrier(0);
      __builtin_amdgcn_s_barrier();
    }
  }

  #pragma unroll
  for (int qm=0;qm<2;qm++)
    #pragma unroll
    for (int qn=0;qn<2;qn++)
      #pragma unroll
      for (int mi=0;mi<4;mi++)
        #pragma unroll
        for (int ni=0;ni<2;ni++){
          const int r = bm*256 + qm*128 + wm*64 + mi*16 + ((lane>>4)<<2);
          const int c = bn*256 + qn*128 + wn*32 + ni*16 + (lane&15);
          float* Cb = C + (size_t)b*sCb;
          #pragma unroll
          for (int j=0;j<4;j++)
            Cb[(size_t)(r+j)*ldc + c] = acc[qm][qn][mi][ni][j];
        }
}

// ---------- fp16 GEMM 128x128 (t1), 8 waves ----------
__global__ __launch_bounds__(512,4) void gemm_t1_k(
    const u16* __restrict__ A_g, const u16* __restrict__ B_g,
    const float* __restrict__ bias, u16* __restrict__ Oh){
  __shared__ __align__(16) u16 As[128*64];
  __shared__ __align__(16) u16 Bs[128*64];
  const int bx = xcd_swz(blockIdx.x, gridDim.x);
  const int bm = bx >> 3, bn = bx & 7;
  const int tid = threadIdx.x, wave = tid>>6, lane = tid&63;
  const int wr = wave>>2, wc = wave&3;
  const u16* Ab = A_g + (size_t)(bm*128)*DD;
  const u16* Bb = B_g + (size_t)(bn*128)*DD;
  f32x4 acc[4][2];
  #pragma unroll
  for (int i=0;i<4;i++)
    #pragma unroll
    for (int j=0;j<2;j++) acc[i][j] = (f32x4){0.f,0.f,0.f,0.f};

  for (int k0 = 0; k0 < DD; k0 += 64){
    __syncthreads();
    stage_tile8(As, Ab + k0, DD, wave, lane);
    stage_tile8(Bs, Bb + k0, DD, wave, lane);
    __syncthreads();
    #pragma unroll
    for (int kk=0;kk<2;kk++){
      const int ko = kk*32 + ((lane>>4)<<3);
      f16x8 a[4], bb[2];
      #pragma unroll
      for (int mi=0;mi<4;mi++) a[mi]  = frag_ld(As, wr*64 + mi*16 + (lane&15), ko);
      #pragma unroll
      for (int ni=0;ni<2;ni++) bb[ni] = frag_ld(Bs, wc*32 + ni*16 + (lane&15), ko);
      #pragma unroll
      for (int mi=0;mi<4;mi++)
        #pragma unroll
        for (int ni=0;ni<2;ni++)
          acc[mi][ni] = __builtin_amdgcn_mfma_f32_16x16x32_f16(a[mi], bb[ni], acc[mi][ni], 0,0,0);
    }
  }
  #pragma unroll
  for (int mi=0;mi<4;mi++)
    #pragma unroll
    for (int ni=0;ni<2;ni++){
      const int r = bm*128 + wr*64 + mi*16 + ((lane>>4)<<2);
      const int c = bn*128 + wc*32 + ni*16 + (lane&15);
      const float bv = bias[c];
      #pragma unroll
      for (int j=0;j<4;j++)
        Oh[(size_t)(r+j)*DD + c] = f2h(acc[mi][ni][j] + bv);
    }
}

// ---------- kernel: row softmax f32->fp16 in place ----------
__global__ __launch_bounds__(256) void softmax_k(float* __restrict__ sim){
  const int row = blockIdx.x;
  float* p = sim + (size_t)row * LL;
  const int tid = threadIdx.x, wave = tid>>6, lane = tid&63;
  f32x4 x0 = reinterpret_cast<const f32x4*>(p)[tid];
  f32x4 x1 = reinterpret_cast<const f32x4*>(p)[tid + 256];
  float mx = fmaxf(fmaxf(fmaxf(x0[0],x0[1]), fmaxf(x0[2],x0[3])),
                   fmaxf(fmaxf(x1[0],x1[1]), fmaxf(x1[2],x1[3])));
  #pragma unroll
  for (int o = 32; o; o >>= 1) mx = fmaxf(mx, __shfl_xor(mx, o, 64));
  __shared__ float red[8];
  if (lane == 0) red[wave] = mx;
  __syncthreads();
  mx = fmaxf(fmaxf(red[0], red[1]), fmaxf(red[2], red[3]));
  float e0[4], e1[4], s = 0.f;
  #pragma unroll
  for (int j=0;j<4;j++){ e0[j] = __expf(x0[j]-mx); s += e0[j]; }
  #pragma unroll
  for (int j=0;j<4;j++){ e1[j] = __expf(x1[j]-mx); s += e1[j]; }
  #pragma unroll
  for (int o = 32; o; o >>= 1) s += __shfl_xor(s, o, 64);
  if (lane == 0) red[4+wave] = s;
  __syncthreads();
  s = (red[4]+red[5]) + (red[6]+red[7]);
  const float inv = 1.0f / s;
  u16* ob = reinterpret_cast<u16*>(p);
  u16x4 w0, w1;
  #pragma unroll
  for (int j=0;j<4;j++){ w0[j] = f2h(e0[j]*inv); w1[j] = f2h(e1[j]*inv); }
  reinterpret_cast<u16x4*>(ob)[tid]       = w0;
  reinterpret_cast<u16x4*>(ob)[tid + 256] = w1;
}

// ---------- kernel: ZT = (t1 @ W2^T)^T fp16, 128-tile, LDS-staged coalesced out ----------
__global__ __launch_bounds__(512,4) void gemm_zt_k(const u16* __restrict__ t1f,
                                                   const u16* __restrict__ w2f,
                                                   u16* __restrict__ ZT){
  __shared__ __align__(16) u16 As[128*64];
  __shared__ __align__(16) u16 Bs[128*64];
  __shared__ u16 T[128*132];               // [m][d] pad 132 vs bank conflicts
  const int bx = xcd_swz(blockIdx.x, gridDim.x);
  const int bm = bx >> 3, bn = bx & 7;
  const int tid = threadIdx.x, wave = tid>>6, lane = tid&63;
  const int wr = wave>>2, wc = wave&3;
  const u16* Ab = t1f + (size_t)(bm*128)*DD;
  const u16* Bb = w2f + (size_t)(bn*128)*DD;
  f32x4 acc[4][2];
  #pragma unroll
  for (int i=0;i<4;i++)
    #pragma unroll
    for (int j=0;j<2;j++) acc[i][j] = (f32x4){0.f,0.f,0.f,0.f};

  for (int k0 = 0; k0 < DD; k0 += 64){
    __syncthreads();
    stage_tile8(As, Ab + k0, DD, wave, lane);
    stage_tile8(Bs, Bb + k0, DD, wave, lane);
    __syncthreads();
    #pragma unroll
    for (int kk=0;kk<2;kk++){
      const int ko = kk*32 + ((lane>>4)<<3);
      f16x8 a[4], bb[2];
      #pragma unroll
      for (int mi=0;mi<4;mi++) a[mi]  = frag_ld(As, wr*64 + mi*16 + (lane&15), ko);
      #pragma unroll
      for (int ni=0;ni<2;ni++) bb[ni] = frag_ld(Bs, wc*32 + ni*16 + (lane&15), ko);
      #pragma unroll
      for (int mi=0;mi<4;mi++)
        #pragma unroll
        for (int ni=0;ni<2;ni++)
          acc[mi][ni] = __builtin_amdgcn_mfma_f32_16x16x32_f16(a[mi], bb[ni], acc[mi][ni], 0,0,0);
    }
  }
  // stage output tile [m=128][d=128] into LDS
  #pragma unroll
  for (int mi=0;mi<4;mi++)
    #pragma unroll
    for (int ni=0;ni<2;ni++){
      const int r = wr*64 + mi*16 + ((lane>>4)<<2);
      const int c = wc*32 + ni*16 + (lane&15);
      #pragma unroll
      for (int j=0;j<4;j++)
        T[(r+j)*132 + c] = f2h(acc[mi][ni][j]);
    }
  __syncthreads();
  // coalesced d-major write: thread -> (d = tid>>2, m0 = (tid&3)*32), 64B contig
  const int b2i = bm >> 4;                     // (bm*128)>>11
  const int mb  = (bm*128) & 2047;
  const int d   = tid >> 2, m0 = (tid & 3) << 5;
  u16* dst = ZT + ((size_t)b2i*DD + bn*128 + d)*LL + mb + m0;
  #pragma unroll
  for (int g = 0; g < 4; ++g){
    u16x8 v;
    #pragma unroll
    for (int e = 0; e < 8; ++e) v[e] = T[(m0 + g*8 + e)*132 + d];
    *reinterpret_cast<u16x8*>(dst + g*8) = v;
  }
}

// ---------- kernel: merged PV GEMM (round-4 structure) ----------
// A = attn fp16 [b][2048] rows at stride 4096 elems. B per bn: bn<8 -> f2T, else ZT.
__global__ __launch_bounds__(512,4) void gemm_pv_k(const u16* __restrict__ attn,
                                                   const u16* __restrict__ f2T,
                                                   const u16* __restrict__ ZT,
                                                   float* __restrict__ out1,
                                                   float* __restrict__ out2,
                                                   const float* __restrict__ b2){
  __shared__ __align__(16) u16 As[128*64];
  __shared__ __align__(16) u16 Bs[128*64];
  const int b = blockIdx.y;
  const int bx = xcd_swz(blockIdx.x, gridDim.x);
  const int bm = bx >> 4, bn = bx & 15;
  const int tid = threadIdx.x, wave = tid>>6, lane = tid&63;
  const int wr = wave>>2, wc = wave&3;
  const u16* Ab = attn + (size_t)b*LL*4096 + (size_t)(bm*128)*4096;
  const u16* Bbase = (bn < 8) ? f2T : ZT;
  const int d0 = (bn & 7) * 128;
  const u16* Bb = Bbase + (size_t)b*DD*LL + (size_t)d0*LL;
  f32x4 acc[4][2];
  #pragma unroll
  for (int i=0;i<4;i++)
    #pragma unroll
    for (int j=0;j<2;j++) acc[i][j] = (f32x4){0.f,0.f,0.f,0.f};

  for (int k0 = 0; k0 < LL; k0 += 64){
    __syncthreads();
    stage_tile8(As, Ab + k0, 4096, wave, lane);
    stage_tile8(Bs, Bb + k0, LL, wave, lane);
    __syncthreads();
    #pragma unroll
    for (int kk=0;kk<2;kk++){
      const int ko = kk*32 + ((lane>>4)<<3);
      f16x8 a[4], bb[2];
      #pragma unroll
      for (int mi=0;mi<4;mi++) a[mi]  = frag_ld(As, wr*64 + mi*16 + (lane&15), ko);
      #pragma unroll
      for (int ni=0;ni<2;ni++) bb[ni] = frag_ld(Bs, wc*32 + ni*16 + (lane&15), ko);
      #pragma unroll
      for (int mi=0;mi<4;mi++)
        #pragma unroll
        for (int ni=0;ni<2;ni++)
          acc[mi][ni] = __builtin_amdgcn_mfma_f32_16x16x32_f16(a[mi], bb[ni], acc[mi][ni], 0,0,0);
    }
  }
  float* O = ((bn < 8) ? out1 : out2) + (size_t)b*LL*DD;
  const bool has_bias = (bn >= 8);
  #pragma unroll
  for (int mi=0;mi<4;mi++)
    #pragma unroll
    for (int ni=0;ni<2;ni++){
      const int r = bm*128 + wr*64 + mi*16 + ((lane>>4)<<2);
      const int c = d0 + wc*32 + ni*16 + (lane&15);
      const float bv = has_bias ? b2[c] : 0.f;
      #pragma unroll
      for (int j=0;j<4;j++)
        O[(size_t)(r+j)*DD + c] = acc[mi][ni][j] + bv;
    }
}

// ---------- host launch ----------
extern "C" void kernel_launch(void* const* d_in, const int* in_sizes, int n_in,
                              void* d_out, int out_size, void* d_ws, size_t ws_size,
                              hipStream_t stream) {
  const float* f1 = (const float*)d_in[0];
  const float* f2 = (const float*)d_in[1];
  const float* W1 = (const float*)d_in[2];
  const float* b1 = (const float*)d_in[3];
  const float* W2 = (const float*)d_in[4];
  const float* b2 = (const float*)d_in[5];
  float* out1 = (float*)d_out;
  float* out2 = out1 + (size_t)BB*LL*DD;

  // workspace layout (bytes); peak 132 MB
  char* ws = (char*)d_ws;
  u16* t1f = (u16*)(ws + 0);              // 16 MiB  fp16 t1 [b*2048][1024]
  u16* ZT  = (u16*)(ws + 16777216);       // 16 MiB  fp16 Z^T [b][1024][2048]
  u16* f2f = (u16*)(ws + 33554432);       // 16 MiB  fp16 f2 [b][2048][1024]
  u16* f2T = (u16*)(ws + 50331648);       // 16 MiB  fp16 f2^T [b][1024][2048]
  u16* w1f = (u16*)(ws + 67108864);       // 2 MiB
  u16* w2f = (u16*)(ws + 69206016);       // 2 MiB
  float* sim = (float*)(ws + 71303168);   // 64 MiB f32; attn fp16 written in place
  u16* f1f = (u16*)(ws + 71303168);       // 16 MiB, aliases sim (dead before sim GEMM)

  // 1. casts: f2 (+transpose) and f1/W1/W2 fused
  castT_k<<<dim3(32, 64, BB), dim3(32, 8), 0, stream>>>(f2, f2f, f2T);
  cast3_k<<<4096, 256, 0, stream>>>(f1, f1f, W1, w1f, W2, w2f);
  // 2. t1 = f1 @ W1^T + b1 (fp16), 128-tile. tiles 64x8.
  gemm_t1_k<<<dim3(512, 1), 512, 0, stream>>>(f1f, w1f, b1, t1f);
  // 3. sim[b] = t1[b] @ f2[b]^T — 8-phase 256x256. tiles 8x8 per batch, NT=16.
  gemm8p_k<<<dim3(64, BB), 512, 0, stream>>>(t1f, (long long)LL*DD, DD,
                                             f2f, (long long)LL*DD, DD,
                                             sim, (long long)LL*LL, LL, 16);
  // 4. softmax rows, write attn fp16 in place (row stride 4096 elems)
  softmax_k<<<BB*LL, 256, 0, stream>>>(sim);
  // 5. ZT = (t1 @ W2^T)^T fp16 (coalesced epilogue)
  gemm_zt_k<<<dim3(512, 1), 512, 0, stream>>>(t1f, w2f, ZT);
  // 6. merged PV (round-4 structure): bn<8 -> out1 = attn@f2, else out2 = attn@Z + b2
  gemm_pv_k<<<dim3(256, BB), 512, 0, stream>>>((const u16*)sim, f2T, ZT,
                                               out1, out2, b2);
}